// Round 1
// baseline (234.639 us; speedup 1.0000x reference)
//
#include <hip/hip_runtime.h>

typedef __attribute__((ext_vector_type(8))) short bf16x8;
typedef __attribute__((ext_vector_type(4))) float f32x4;
typedef __attribute__((ext_vector_type(4))) int i32x4;

#define NB 4
#define NN 4096
#define NH 4
#define ND 32
#define NEG_SL 0.2f
#define BQ 64
#define BK 128

static __device__ __forceinline__ ushort f32_to_bf16(float f) {
  unsigned u = __float_as_uint(f);
  unsigned r = 0x7fffu + ((u >> 16) & 1u);
  return (ushort)((u + r) >> 16);
}
static __device__ __forceinline__ float bf16_to_f32(ushort h) {
  return __uint_as_float(((unsigned)h) << 16);
}

// ---------------------------------------------------------------------------
// Projection: Wh[b,n,o] = sum_i h[b,n,i] * W[o,i]
// Output layout: whh/whl [B][H][N][D] bf16 (hi and lo residual planes)
// ---------------------------------------------------------------------------
__global__ __launch_bounds__(256) void proj_kernel(const float* __restrict__ hm,
                                                   const float* __restrict__ Wm,
                                                   ushort* __restrict__ whh,
                                                   ushort* __restrict__ whl) {
  __shared__ float sWT[128 * 128];  // sWT[k][o] = W[o][k]
  __shared__ float sH[64][128];

  const int t = threadIdx.x;
  const long rowbase = (long)blockIdx.x * 64;  // global n-row over B*N

  // stage W transposed (chunk i: o = i&127, k4 = i>>7)
  for (int i = t; i < 4096; i += 256) {
    const int o = i & 127, k4 = i >> 7;
    const float4 w = *(const float4*)(Wm + o * 128 + k4 * 4);
    sWT[(k4 * 4 + 0) * 128 + o] = w.x;
    sWT[(k4 * 4 + 1) * 128 + o] = w.y;
    sWT[(k4 * 4 + 2) * 128 + o] = w.z;
    sWT[(k4 * 4 + 3) * 128 + o] = w.w;
  }
  // stage 64 h rows
  for (int i = t; i < 64 * 128 / 4; i += 256) {
    *((float4*)(&sH[0][0]) + i) = *((const float4*)(hm + rowbase * 128) + i);
  }
  __syncthreads();

  const int oc = (t & 31) * 4;  // 4 output cols
  const int nr = (t >> 5) * 8;  // 8 local rows

  float acc[8][4];
#pragma unroll
  for (int r = 0; r < 8; ++r)
#pragma unroll
    for (int j = 0; j < 4; ++j) acc[r][j] = 0.f;

  for (int k = 0; k < 128; ++k) {
    const float4 wv = *(const float4*)(&sWT[k * 128 + oc]);
#pragma unroll
    for (int r = 0; r < 8; ++r) {
      const float hv = sH[nr + r][k];
      acc[r][0] = fmaf(hv, wv.x, acc[r][0]);
      acc[r][1] = fmaf(hv, wv.y, acc[r][1]);
      acc[r][2] = fmaf(hv, wv.z, acc[r][2]);
      acc[r][3] = fmaf(hv, wv.w, acc[r][3]);
    }
  }

  const int hh = oc >> 5;   // head index
  const int d0 = oc & 31;   // d within head
#pragma unroll
  for (int r = 0; r < 8; ++r) {
    const long gn = rowbase + nr + r;
    const long b = gn >> 12;      // / 4096
    const long n = gn & 4095;
    unsigned hi_[4], lo_[4];
#pragma unroll
    for (int j = 0; j < 4; ++j) {
      const float v = acc[r][j];
      const ushort h16 = f32_to_bf16(v);
      const float rem = v - bf16_to_f32(h16);
      hi_[j] = h16;
      lo_[j] = f32_to_bf16(rem);
    }
    const size_t idx = (((size_t)(b * NH + hh)) * NN + n) * ND + d0;
    uint2 ph, pl;
    ph.x = hi_[0] | (hi_[1] << 16);
    ph.y = hi_[2] | (hi_[3] << 16);
    pl.x = lo_[0] | (lo_[1] << 16);
    pl.y = lo_[2] | (lo_[3] << 16);
    *(uint2*)(whh + idx) = ph;
    *(uint2*)(whl + idx) = pl;
  }
}

// ---------------------------------------------------------------------------
// Flash attention per (b,h): Q=K=V=Wh[b,:,h,:]  (N x 32)
// scores -> leaky_relu -> online softmax -> PV, hi/lo split on QK^T
// ---------------------------------------------------------------------------
__global__ __launch_bounds__(256) void attn_kernel(const ushort* __restrict__ whh,
                                                   const ushort* __restrict__ whl,
                                                   float* __restrict__ out) {
  __shared__ ushort sKh[BK * 32];        // swizzled rows of 64B
  __shared__ ushort sKl[BK * 32];
  __shared__ ushort sVt[32 * BK];        // V^T, swizzled rows of 256B
  __shared__ ushort sP[4][16 * BK];      // per-wave P tile, swizzled rows of 256B

  const int t = threadIdx.x;
  const int wid = t >> 6;
  const int lane = t & 63;
  const int qr = lane & 15;   // fragment row/col index
  const int kg = lane >> 4;   // k-group 0..3

  const int bid = blockIdx.x;
  const int qt = bid & (NN / BQ - 1);  // 0..63
  const int bh = bid >> 6;             // 0..15 = b*H + h
  const ushort* __restrict__ baseh = whh + (size_t)bh * NN * ND;
  const ushort* __restrict__ basel = whl + (size_t)bh * NN * ND;

  const int q0 = qt * BQ + wid * 16;

  // Q fragments (A-operand): lane holds Q[qr][kg*8 + j], j=0..7
  const bf16x8 qfh = *(const bf16x8*)(baseh + (size_t)(q0 + qr) * ND + kg * 8);
  const bf16x8 qfl = *(const bf16x8*)(basel + (size_t)(q0 + qr) * ND + kg * 8);

  f32x4 o0 = {0.f, 0.f, 0.f, 0.f};
  f32x4 o1 = {0.f, 0.f, 0.f, 0.f};
  float m[4], l[4];
#pragma unroll
  for (int r = 0; r < 4; ++r) { m[r] = -INFINITY; l[r] = 0.f; }

  for (int kt = 0; kt < NN; kt += BK) {
    __syncthreads();
    // ---- stage K tile: Kh, Kl row-major [BK][32]; Vt = K^T [32][BK] ----
#pragma unroll
    for (int c0 = 0; c0 < 2; ++c0) {
      const int c = c0 * 256 + t;       // 0..511, chunk = (row, 16B-slot s)
      const int row = c >> 2, s = c & 3;
      const i32x4 vh = *(const i32x4*)(baseh + (size_t)(kt + row) * ND + s * 8);
      const i32x4 vl = *(const i32x4*)(basel + (size_t)(kt + row) * ND + s * 8);
      const int dst = row * 64 + ((s * 16) ^ ((row & 3) << 4));
      *(i32x4*)((char*)sKh + dst) = vh;
      *(i32x4*)((char*)sKl + dst) = vl;
      // scatter hi elements into V^T
#pragma unroll
      for (int j = 0; j < 8; ++j) {
        const int d = s * 8 + j;
        const int word = vh[j >> 1];
        const ushort e = (ushort)((j & 1) ? (((unsigned)word) >> 16) : (word & 0xffff));
        const int off = d * (2 * BK) + ((row * 2) ^ ((d & 7) << 4));
        *(ushort*)((char*)sVt + off) = e;
      }
    }
    __syncthreads();

    // ---- scores S = Qh*Kh + Qh*Kl + Ql*Kh  (16 x 128 per wave) ----
    f32x4 acc[8];
#pragma unroll
    for (int ks = 0; ks < 8; ++ks) {
      const int krow = ks * 16 + qr;
      const int koff = krow * 64 + ((kg * 16) ^ ((krow & 3) << 4));
      const bf16x8 khf = *(const bf16x8*)((const char*)sKh + koff);
      const bf16x8 klf = *(const bf16x8*)((const char*)sKl + koff);
      f32x4 z = {0.f, 0.f, 0.f, 0.f};
      z = __builtin_amdgcn_mfma_f32_16x16x32_bf16(qfh, klf, z, 0, 0, 0);
      z = __builtin_amdgcn_mfma_f32_16x16x32_bf16(qfl, khf, z, 0, 0, 0);
      z = __builtin_amdgcn_mfma_f32_16x16x32_bf16(qfh, khf, z, 0, 0, 0);
      acc[ks] = z;
    }

    // ---- leaky relu + row max (rows live on 16-lane groups) ----
    float pm[4];
#pragma unroll
    for (int r = 0; r < 4; ++r) pm[r] = -INFINITY;
#pragma unroll
    for (int ks = 0; ks < 8; ++ks)
#pragma unroll
      for (int r = 0; r < 4; ++r) {
        float x = acc[ks][r];
        x = (x > 0.f) ? x : (NEG_SL * x);
        acc[ks][r] = x;
        pm[r] = fmaxf(pm[r], x);
      }
#pragma unroll
    for (int mask = 1; mask <= 8; mask <<= 1)
#pragma unroll
      for (int r = 0; r < 4; ++r) pm[r] = fmaxf(pm[r], __shfl_xor(pm[r], mask, 64));

    float sc[4];
#pragma unroll
    for (int r = 0; r < 4; ++r) {
      const float mn = fmaxf(m[r], pm[r]);
      sc[r] = __expf(m[r] - mn);
      m[r] = mn;
      l[r] *= sc[r];
    }
#pragma unroll
    for (int r = 0; r < 4; ++r) { o0[r] *= sc[r]; o1[r] *= sc[r]; }

    // ---- p = exp(x - m); accumulate row sums; write P to per-wave LDS ----
    float rs[4];
#pragma unroll
    for (int r = 0; r < 4; ++r) rs[r] = 0.f;
#pragma unroll
    for (int ks = 0; ks < 8; ++ks)
#pragma unroll
      for (int r = 0; r < 4; ++r) {
        const float p = __expf(acc[ks][r] - m[r]);
        rs[r] += p;
        const int qlocal = kg * 4 + r;          // C-layout row
        const int col = ks * 16 + qr;           // C-layout col
        const int off = qlocal * (2 * BK) + ((col * 2) ^ ((qlocal & 7) << 4));
        *(ushort*)((char*)&sP[wid][0] + off) = f32_to_bf16(p);
      }
#pragma unroll
    for (int mask = 1; mask <= 8; mask <<= 1)
#pragma unroll
      for (int r = 0; r < 4; ++r) rs[r] += __shfl_xor(rs[r], mask, 64);
#pragma unroll
    for (int r = 0; r < 4; ++r) l[r] += rs[r];

    // ---- PV: O += P * V ----
#pragma unroll
    for (int kp = 0; kp < 4; ++kp) {
      const int k0 = kp * 32 + kg * 8;
      const int poff = qr * (2 * BK) + ((k0 * 2) ^ ((qr & 7) << 4));
      const bf16x8 pf = *(const bf16x8*)((const char*)&sP[wid][0] + poff);
      const int voff0 = qr * (2 * BK) + ((k0 * 2) ^ ((qr & 7) << 4));
      const int voff1 = (16 + qr) * (2 * BK) + ((k0 * 2) ^ ((qr & 7) << 4));
      const bf16x8 vf0 = *(const bf16x8*)((const char*)sVt + voff0);
      const bf16x8 vf1 = *(const bf16x8*)((const char*)sVt + voff1);
      o0 = __builtin_amdgcn_mfma_f32_16x16x32_bf16(pf, vf0, o0, 0, 0, 0);
      o1 = __builtin_amdgcn_mfma_f32_16x16x32_bf16(pf, vf1, o1, 0, 0, 0);
    }
  }

  // ---- epilogue: normalize and store ----
  const int b = bh >> 2, hh = bh & 3;
#pragma unroll
  for (int r = 0; r < 4; ++r) {
    const int q = q0 + kg * 4 + r;
    const float inv = 1.f / l[r];
    const size_t rowoff = ((size_t)(b * NN + q)) * 128 + hh * 32;
    out[rowoff + qr] = o0[r] * inv;
    out[rowoff + 16 + qr] = o1[r] * inv;
  }
}

extern "C" void kernel_launch(void* const* d_in, const int* in_sizes, int n_in,
                              void* d_out, int out_size, void* d_ws, size_t ws_size,
                              hipStream_t stream) {
  const float* hm = (const float*)d_in[0];
  const float* Wm = (const float*)d_in[1];
  float* out = (float*)d_out;
  ushort* whh = (ushort*)d_ws;
  ushort* whl = whh + (size_t)NB * NH * NN * ND;  // +2M elements (4 MB)

  proj_kernel<<<NB * NN / 64, 256, 0, stream>>>(hm, Wm, whh, whl);
  attn_kernel<<<NB * NH * (NN / BQ), 256, 0, stream>>>(whh, whl, out);
}

// Round 5
// 209.243 us; speedup vs baseline: 1.1214x; 1.1214x over previous
//
#include <hip/hip_runtime.h>

typedef __attribute__((ext_vector_type(8))) short bf16x8;
typedef __attribute__((ext_vector_type(4))) float f32x4;
typedef __attribute__((ext_vector_type(4))) int i32x4;
typedef __attribute__((ext_vector_type(2))) unsigned int u32x2;

#define NB 4
#define NN 4096
#define NH 4
#define ND 32
#define NEG_SL 0.2f
#define BQ 64
#define BK 128
#define VSTR 264   // sVt row stride bytes: 256 data + 8 pad (bank spread, 8B aligned)

static __device__ __forceinline__ ushort f32_to_bf16(float f) {
  unsigned u = __float_as_uint(f);
  unsigned r = 0x7fffu + ((u >> 16) & 1u);
  return (ushort)((u + r) >> 16);
}
static __device__ __forceinline__ float bf16_to_f32(ushort h) {
  return __uint_as_float(((unsigned)h) << 16);
}
// pack two f32 -> one u32 of 2 bf16 (round-half-up); elem0 = a (low half)
static __device__ __forceinline__ unsigned pack_bf16_2(float a, float b) {
  const unsigned ua = (__float_as_uint(a) + 0x8000u) >> 16;
  const unsigned ub = (__float_as_uint(b) + 0x8000u) & 0xffff0000u;
  return ua | ub;
}
static __device__ __forceinline__ bf16x8 as_bf16x8(i32x4 v) {
  union { i32x4 i; bf16x8 b; } u; u.i = v; return u.b;
}

// ---------------------------------------------------------------------------
// Projection (round-1 proven, byte-identical): Wh = h @ W^T -> hi/lo bf16
// ---------------------------------------------------------------------------
__global__ __launch_bounds__(256) void proj_kernel(const float* __restrict__ hm,
                                                   const float* __restrict__ Wm,
                                                   ushort* __restrict__ whh,
                                                   ushort* __restrict__ whl) {
  __shared__ float sWT[128 * 128];
  __shared__ float sH[64][128];

  const int t = threadIdx.x;
  const long rowbase = (long)blockIdx.x * 64;

  for (int i = t; i < 4096; i += 256) {
    const int o = i & 127, k4 = i >> 7;
    const float4 w = *(const float4*)(Wm + o * 128 + k4 * 4);
    sWT[(k4 * 4 + 0) * 128 + o] = w.x;
    sWT[(k4 * 4 + 1) * 128 + o] = w.y;
    sWT[(k4 * 4 + 2) * 128 + o] = w.z;
    sWT[(k4 * 4 + 3) * 128 + o] = w.w;
  }
  for (int i = t; i < 64 * 128 / 4; i += 256) {
    *((float4*)(&sH[0][0]) + i) = *((const float4*)(hm + rowbase * 128) + i);
  }
  __syncthreads();

  const int oc = (t & 31) * 4;
  const int nr = (t >> 5) * 8;

  float acc[8][4];
#pragma unroll
  for (int r = 0; r < 8; ++r)
#pragma unroll
    for (int j = 0; j < 4; ++j) acc[r][j] = 0.f;

  for (int k = 0; k < 128; ++k) {
    const float4 wv = *(const float4*)(&sWT[k * 128 + oc]);
#pragma unroll
    for (int r = 0; r < 8; ++r) {
      const float hv = sH[nr + r][k];
      acc[r][0] = fmaf(hv, wv.x, acc[r][0]);
      acc[r][1] = fmaf(hv, wv.y, acc[r][1]);
      acc[r][2] = fmaf(hv, wv.z, acc[r][2]);
      acc[r][3] = fmaf(hv, wv.w, acc[r][3]);
    }
  }

  const int hh = oc >> 5;
  const int d0 = oc & 31;
#pragma unroll
  for (int r = 0; r < 8; ++r) {
    const long gn = rowbase + nr + r;
    const long b = gn >> 12;
    const long n = gn & 4095;
    unsigned hi_[4], lo_[4];
#pragma unroll
    for (int j = 0; j < 4; ++j) {
      const float v = acc[r][j];
      const ushort h16 = f32_to_bf16(v);
      hi_[j] = h16;
      lo_[j] = f32_to_bf16(v - bf16_to_f32(h16));
    }
    const size_t idx = (((size_t)(b * NH + hh)) * NN + n) * ND + d0;
    uint2 ph, pl;
    ph.x = hi_[0] | (hi_[1] << 16);
    ph.y = hi_[2] | (hi_[3] << 16);
    pl.x = lo_[0] | (lo_[1] << 16);
    pl.y = lo_[2] | (lo_[3] << 16);
    *(uint2*)(whh + idx) = ph;
    *(uint2*)(whl + idx) = pl;
  }
}

// ---------------------------------------------------------------------------
// Flash attention (round-1 structure: A=Q, B=K). New: paired-P LDS round trip
// (b128 instead of 32x u16), sigma-matched V^T layout, reg-prefetch staging,
// XCD-swizzled grid. Scores/softmax/epilogue identical to the passing round 1.
// ---------------------------------------------------------------------------
__global__ __launch_bounds__(256) void attn_kernel(const ushort* __restrict__ whh,
                                                   const ushort* __restrict__ whl,
                                                   float* __restrict__ out) {
  __shared__ ushort sKh[BK * 32];                 // round-1 layout (64B rows, swz)
  __shared__ ushort sKl[BK * 32];
  __shared__ __align__(16) char sVt[32 * VSTR];   // pi-layout V^T (see scatter)
  __shared__ __align__(16) char sP[4][4096];      // per-wave paired P tile

  const int t = threadIdx.x;
  const int wid = t >> 6;
  const int lane = t & 63;
  const int qr = lane & 15;
  const int kg = lane >> 4;

  int bid = blockIdx.x;
  bid = (bid & 7) * 128 + (bid >> 3);             // XCD swizzle (1024 % 8 == 0)
  const int qt = bid & (NN / BQ - 1);
  const int bh = bid >> 6;
  const ushort* __restrict__ baseh = whh + (size_t)bh * NN * ND;
  const ushort* __restrict__ basel = whl + (size_t)bh * NN * ND;

  const int q0 = qt * BQ + wid * 16;

  // Q fragments (A-operand): lane holds Q[qr][kg*8 + j]
  const bf16x8 qfh = *(const bf16x8*)(baseh + (size_t)(q0 + qr) * ND + kg * 8);
  const bf16x8 qfl = *(const bf16x8*)(basel + (size_t)(q0 + qr) * ND + kg * 8);

  f32x4 o0 = {0.f, 0.f, 0.f, 0.f};
  f32x4 o1 = {0.f, 0.f, 0.f, 0.f};
  float m[4], l[4];
#pragma unroll
  for (int r = 0; r < 4; ++r) { m[r] = -INFINITY; l[r] = 0.f; }

  // staging geometry (round-1 chunking): chunk c = c0*256 + t -> row, 16B slot
  const int srow0 = t >> 2;      // + c0*64
  const int ss = t & 3;

  // prefetch tile 0 into registers
  i32x4 vh[2], vl[2];
#pragma unroll
  for (int c0 = 0; c0 < 2; ++c0) {
    const int row = c0 * 64 + srow0;
    vh[c0] = *(const i32x4*)(baseh + (size_t)row * ND + ss * 8);
    vl[c0] = *(const i32x4*)(basel + (size_t)row * ND + ss * 8);
  }

  for (int kt6 = 0; kt6 < 32; ++kt6) {
    __syncthreads();
    // ---- stage K tile (round-1 sK layout) + sigma-matched V^T scatter ----
#pragma unroll
    for (int c0 = 0; c0 < 2; ++c0) {
      const int row = c0 * 64 + srow0;
      const int dst = row * 64 + ((ss * 16) ^ ((row & 3) << 4));
      *(i32x4*)((char*)sKh + dst) = vh[c0];
      *(i32x4*)((char*)sKl + dst) = vl[c0];
      // V^T: element (row, d) at byte d*VSTR + ((row&15)^ (d&7))*16 + (row>>4)*2
#pragma unroll
      for (int j = 0; j < 8; ++j) {
        const int word = vh[c0][j >> 1];
        const ushort e = (ushort)((j & 1) ? (((unsigned)word) >> 16) : (word & 0xffff));
        const int d = ss * 8 + j;
        const int off = d * VSTR + (((row & 15) ^ j) * 16) + ((row >> 4) * 2);
        *(ushort*)(&sVt[off]) = e;
      }
    }
    // ---- prefetch next tile into registers (hides under compute) ----
    const int ktn = ((kt6 + 1) & 31) * BK;
#pragma unroll
    for (int c0 = 0; c0 < 2; ++c0) {
      const int row = ktn + c0 * 64 + srow0;
      vh[c0] = *(const i32x4*)(baseh + (size_t)row * ND + ss * 8);
      vl[c0] = *(const i32x4*)(basel + (size_t)row * ND + ss * 8);
    }
    __syncthreads();

    // ---- scores S = Qh*Kh + Qh*Kl + Ql*Kh (round-1 verified) ----
    f32x4 acc[8];
#pragma unroll
    for (int ks = 0; ks < 8; ++ks) {
      const int krow = ks * 16 + qr;
      const int koff = krow * 64 + ((kg * 16) ^ ((krow & 3) << 4));
      const bf16x8 khf = *(const bf16x8*)((const char*)sKh + koff);
      const bf16x8 klf = *(const bf16x8*)((const char*)sKl + koff);
      f32x4 z = {0.f, 0.f, 0.f, 0.f};
      z = __builtin_amdgcn_mfma_f32_16x16x32_bf16(qfh, klf, z, 0, 0, 0);
      z = __builtin_amdgcn_mfma_f32_16x16x32_bf16(qfl, khf, z, 0, 0, 0);
      z = __builtin_amdgcn_mfma_f32_16x16x32_bf16(qfh, khf, z, 0, 0, 0);
      acc[ks] = z;
    }

    // ---- leaky relu + row max (round-1 verified) ----
    float pm[4];
#pragma unroll
    for (int r = 0; r < 4; ++r) pm[r] = -INFINITY;
#pragma unroll
    for (int ks = 0; ks < 8; ++ks)
#pragma unroll
      for (int r = 0; r < 4; ++r) {
        float x = acc[ks][r];
        x = (x > 0.f) ? x : (NEG_SL * x);
        acc[ks][r] = x;
        pm[r] = fmaxf(pm[r], x);
      }
#pragma unroll
    for (int mask = 1; mask <= 8; mask <<= 1)
#pragma unroll
      for (int r = 0; r < 4; ++r) pm[r] = fmaxf(pm[r], __shfl_xor(pm[r], mask, 64));

    float sc[4];
#pragma unroll
    for (int r = 0; r < 4; ++r) {
      const float mn = fmaxf(m[r], pm[r]);
      sc[r] = __expf(m[r] - mn);
      m[r] = mn;
      l[r] *= sc[r];
    }
#pragma unroll
    for (int r = 0; r < 4; ++r) { o0[r] *= sc[r]; o1[r] *= sc[r]; }

    // ---- p = exp(x - m); row sums (round-1 verified, LDS write removed) ----
    float rs[4];
#pragma unroll
    for (int r = 0; r < 4; ++r) rs[r] = 0.f;
#pragma unroll
    for (int ks = 0; ks < 8; ++ks)
#pragma unroll
      for (int r = 0; r < 4; ++r) {
        const float p = __expf(acc[ks][r] - m[r]);
        acc[ks][r] = p;
        rs[r] += p;
      }
#pragma unroll
    for (int mask = 1; mask <= 8; mask <<= 1)
#pragma unroll
      for (int r = 0; r < 4; ++r) rs[r] += __shfl_xor(rs[r], mask, 64);
#pragma unroll
    for (int r = 0; r < 4; ++r) l[r] += rs[r];

    // ---- paired-P write: row rho = kg*4+r holds P[rho][e*16 + qr], e = ks ----
#pragma unroll
    for (int r = 0; r < 4; ++r) {
      i32x4 pw;
#pragma unroll
      for (int w = 0; w < 4; ++w)
        pw[w] = (int)pack_bf16_2(acc[2 * w][r], acc[2 * w + 1][r]);
      const int rho = kg * 4 + r;
      const int cb = qr ^ (rho & 7);
      *(i32x4*)(&sP[wid][rho * 256 + cb * 16]) = pw;
    }

    // ---- PV: A = paired P (sigma k-order), B = pi-layout V^T (same sigma) ----
#pragma unroll
    for (int kp = 0; kp < 4; ++kp) {
      const int cbp = (kp * 4 + kg) ^ (qr & 7);
      const bf16x8 pa = *(const bf16x8*)(&sP[wid][qr * 256 + cbp * 16]);
      const int vb0b = qr * VSTR + cbp * 16;
      const int vb1b = (16 + qr) * VSTR + cbp * 16;
      const u32x2 a0 = *(const u32x2*)(&sVt[vb0b]);
      const u32x2 a1 = *(const u32x2*)(&sVt[vb0b + 8]);
      const u32x2 b0 = *(const u32x2*)(&sVt[vb1b]);
      const u32x2 b1 = *(const u32x2*)(&sVt[vb1b + 8]);
      i32x4 v0, v1;
      v0[0] = (int)a0[0]; v0[1] = (int)a0[1]; v0[2] = (int)a1[0]; v0[3] = (int)a1[1];
      v1[0] = (int)b0[0]; v1[1] = (int)b0[1]; v1[2] = (int)b1[0]; v1[3] = (int)b1[1];
      const bf16x8 vb0 = as_bf16x8(v0);
      const bf16x8 vb1 = as_bf16x8(v1);
      o0 = __builtin_amdgcn_mfma_f32_16x16x32_bf16(pa, vb0, o0, 0, 0, 0);
      o1 = __builtin_amdgcn_mfma_f32_16x16x32_bf16(pa, vb1, o1, 0, 0, 0);
    }
  }

  // ---- epilogue (round-1 verified) ----
  const int b = bh >> 2, hh = bh & 3;
#pragma unroll
  for (int r = 0; r < 4; ++r) {
    const int q = q0 + kg * 4 + r;
    const float inv = 1.f / l[r];
    const size_t rowoff = ((size_t)(b * NN + q)) * 128 + hh * 32;
    out[rowoff + qr] = o0[r] * inv;
    out[rowoff + 16 + qr] = o1[r] * inv;
  }
}

extern "C" void kernel_launch(void* const* d_in, const int* in_sizes, int n_in,
                              void* d_out, int out_size, void* d_ws, size_t ws_size,
                              hipStream_t stream) {
  const float* hm = (const float*)d_in[0];
  const float* Wm = (const float*)d_in[1];
  float* out = (float*)d_out;
  ushort* whh = (ushort*)d_ws;
  ushort* whl = whh + (size_t)NB * NH * NN * ND;   // 8 MB total (round-1 proven)

  proj_kernel<<<NB * NN / 64, 256, 0, stream>>>(hm, Wm, whh, whl);
  attn_kernel<<<NB * NH * (NN / BQ), 256, 0, stream>>>(whh, whl, out);
}

// Round 6
// 168.731 us; speedup vs baseline: 1.3906x; 1.2401x over previous
//
#include <hip/hip_runtime.h>

typedef __attribute__((ext_vector_type(8))) short bf16x8;
typedef __attribute__((ext_vector_type(4))) float f32x4;
typedef __attribute__((ext_vector_type(4))) int i32x4;

#define NB 4
#define NN 4096
#define NH 4
#define ND 32
#define NEG_SL 0.2f
#define BQ 128
#define BK 128
#define KSTR 80    // K-tile row stride bytes (64 data + 16 pad) -> slot-even b128
#define VSTR 272   // sVt row stride bytes (256 data + 16 pad), 16B multiple

static __device__ __forceinline__ ushort f32_to_bf16(float f) {
  unsigned u = __float_as_uint(f);
  unsigned r = 0x7fffu + ((u >> 16) & 1u);
  return (ushort)((u + r) >> 16);
}
static __device__ __forceinline__ float bf16_to_f32(ushort h) {
  return __uint_as_float(((unsigned)h) << 16);
}
// pack two f32 -> one u32 of 2 bf16 (round-half-up); elem0 = a (low half)
static __device__ __forceinline__ unsigned pack_bf16_2(float a, float b) {
  const unsigned ua = (__float_as_uint(a) + 0x8000u) >> 16;
  const unsigned ub = (__float_as_uint(b) + 0x8000u) & 0xffff0000u;
  return ua | ub;
}
static __device__ __forceinline__ bf16x8 as_bf16x8(i32x4 v) {
  union { i32x4 i; bf16x8 b; } u; u.i = v; return u.b;
}
// DPP row_ror-based 16-lane allreduce (VALU pipe, replaces ds-shuffles)
template <int CTRL>
static __device__ __forceinline__ float row_ror(float x) {
  return __int_as_float(__builtin_amdgcn_update_dpp(
      __float_as_int(x), __float_as_int(x), CTRL, 0xf, 0xf, true));
}
static __device__ __forceinline__ float rmax16(float v) {
  v = fmaxf(v, row_ror<0x121>(v));   // ror:1
  v = fmaxf(v, row_ror<0x122>(v));   // ror:2
  v = fmaxf(v, row_ror<0x124>(v));   // ror:4
  v = fmaxf(v, row_ror<0x128>(v));   // ror:8
  return v;
}
static __device__ __forceinline__ float rsum16(float v) {
  v += row_ror<0x121>(v);
  v += row_ror<0x122>(v);
  v += row_ror<0x124>(v);
  v += row_ror<0x128>(v);
  return v;
}

// ---------------------------------------------------------------------------
// Projection (round-1 proven, byte-identical): Wh = h @ W^T -> hi/lo bf16
// ---------------------------------------------------------------------------
__global__ __launch_bounds__(256) void proj_kernel(const float* __restrict__ hm,
                                                   const float* __restrict__ Wm,
                                                   ushort* __restrict__ whh,
                                                   ushort* __restrict__ whl) {
  __shared__ float sWT[128 * 128];
  __shared__ float sH[64][128];

  const int t = threadIdx.x;
  const long rowbase = (long)blockIdx.x * 64;

  for (int i = t; i < 4096; i += 256) {
    const int o = i & 127, k4 = i >> 7;
    const float4 w = *(const float4*)(Wm + o * 128 + k4 * 4);
    sWT[(k4 * 4 + 0) * 128 + o] = w.x;
    sWT[(k4 * 4 + 1) * 128 + o] = w.y;
    sWT[(k4 * 4 + 2) * 128 + o] = w.z;
    sWT[(k4 * 4 + 3) * 128 + o] = w.w;
  }
  for (int i = t; i < 64 * 128 / 4; i += 256) {
    *((float4*)(&sH[0][0]) + i) = *((const float4*)(hm + rowbase * 128) + i);
  }
  __syncthreads();

  const int oc = (t & 31) * 4;
  const int nr = (t >> 5) * 8;

  float acc[8][4];
#pragma unroll
  for (int r = 0; r < 8; ++r)
#pragma unroll
    for (int j = 0; j < 4; ++j) acc[r][j] = 0.f;

  for (int k = 0; k < 128; ++k) {
    const float4 wv = *(const float4*)(&sWT[k * 128 + oc]);
#pragma unroll
    for (int r = 0; r < 8; ++r) {
      const float hv = sH[nr + r][k];
      acc[r][0] = fmaf(hv, wv.x, acc[r][0]);
      acc[r][1] = fmaf(hv, wv.y, acc[r][1]);
      acc[r][2] = fmaf(hv, wv.z, acc[r][2]);
      acc[r][3] = fmaf(hv, wv.w, acc[r][3]);
    }
  }

  const int hh = oc >> 5;
  const int d0 = oc & 31;
#pragma unroll
  for (int r = 0; r < 8; ++r) {
    const long gn = rowbase + nr + r;
    const long b = gn >> 12;
    const long n = gn & 4095;
    unsigned hi_[4], lo_[4];
#pragma unroll
    for (int j = 0; j < 4; ++j) {
      const float v = acc[r][j];
      const ushort h16 = f32_to_bf16(v);
      hi_[j] = h16;
      lo_[j] = f32_to_bf16(v - bf16_to_f32(h16));
    }
    const size_t idx = (((size_t)(b * NH + hh)) * NN + n) * ND + d0;
    uint2 ph, pl;
    ph.x = hi_[0] | (hi_[1] << 16);
    ph.y = hi_[2] | (hi_[3] << 16);
    pl.x = lo_[0] | (lo_[1] << 16);
    pl.y = lo_[2] | (lo_[3] << 16);
    *(uint2*)(whh + idx) = ph;
    *(uint2*)(whl + idx) = pl;
  }
}

// ---------------------------------------------------------------------------
// Flash attention (round-5 verified structure, A=Q B=K). Changes: BQ=128
// (2 q-frags/wave), K-stride 80, pair-packed V^T scatter (u32, 2-way free),
// b128 V reads, DPP softmax reductions. All LDS formulas are matched
// write/read pairs of the same F.
// ---------------------------------------------------------------------------
__global__ __launch_bounds__(256) void attn_kernel(const ushort* __restrict__ whh,
                                                   const ushort* __restrict__ whl,
                                                   float* __restrict__ out) {
  __shared__ __align__(16) char sKh[BK * KSTR];     // 10240 B
  __shared__ __align__(16) char sKl[BK * KSTR];     // 10240 B
  __shared__ __align__(16) char sVt[32 * VSTR];     // 8704 B
  __shared__ __align__(16) char sP[4][2][4096];     // 32768 B (per wave, per frag)

  const int t = threadIdx.x;
  const int wid = t >> 6;
  const int lane = t & 63;
  const int qr = lane & 15;
  const int kg = lane >> 4;

  int bid = blockIdx.x;
  bid = (bid & 7) * 64 + (bid >> 3);               // XCD swizzle (512 % 8 == 0)
  const int qt = bid & 31;
  const int bh = bid >> 5;
  const ushort* __restrict__ baseh = whh + (size_t)bh * NN * ND;
  const ushort* __restrict__ basel = whl + (size_t)bh * NN * ND;

  const int q0 = qt * BQ + wid * 32;

  // Q fragments (A-operand): lane holds Q[q0 + qf*16 + qr][kg*8 + j]
  bf16x8 qh[2], ql[2];
#pragma unroll
  for (int qf = 0; qf < 2; ++qf) {
    qh[qf] = *(const bf16x8*)(baseh + (size_t)(q0 + qf * 16 + qr) * ND + kg * 8);
    ql[qf] = *(const bf16x8*)(basel + (size_t)(q0 + qf * 16 + qr) * ND + kg * 8);
  }

  // ---- staging geometry: thread -> (rowpair r0/r0+16, 16B slot s) ----
  const int rp = t >> 2;                           // 0..63
  const int s = t & 3;
  const int r0 = ((rp & ~15) << 1) + (rp & 15);    // {0..15,32..47,64..79,96..111}
  const unsigned gsrc0 = (unsigned)(r0 * ND + s * 8);
  const unsigned gsrc1 = gsrc0 + 16u * ND;
  const unsigned kdst0 = (unsigned)(r0 * KSTR + ((s ^ (r0 & 3)) << 4));
  const unsigned kdst1 = (unsigned)((r0 + 16) * KSTR + ((s ^ (r0 & 3)) << 4));
  // V^T scatter addresses: d = s*8+j, kb = rp&15, c' = (kb&8)|((kb+3d)&7)
  unsigned vaddr[8];
#pragma unroll
  for (int j = 0; j < 8; ++j) {
    const int d = s * 8 + j;
    const int kb = rp & 15;
    const int cs = (kb & 8) | ((kb + 3 * d) & 7);
    vaddr[j] = (unsigned)(d * VSTR + cs * 16 + (rp >> 4) * 4);
  }
  // score read lane-constant: koff(ks) = koffc + ks*16*KSTR  (krow&3 == qr&3)
  const unsigned koffc = (unsigned)(qr * KSTR + ((kg ^ (qr & 3)) << 4));

  f32x4 o[2][2];
#pragma unroll
  for (int qf = 0; qf < 2; ++qf)
#pragma unroll
    for (int pl = 0; pl < 2; ++pl) o[qf][pl] = f32x4{0.f, 0.f, 0.f, 0.f};
  float m_[2][4], l_[2][4];
#pragma unroll
  for (int qf = 0; qf < 2; ++qf)
#pragma unroll
    for (int r = 0; r < 4; ++r) { m_[qf][r] = -INFINITY; l_[qf][r] = 0.f; }

  // prefetch tile 0 into registers
  i32x4 vh0 = *(const i32x4*)(baseh + gsrc0);
  i32x4 vh1 = *(const i32x4*)(baseh + gsrc1);
  i32x4 vl0 = *(const i32x4*)(basel + gsrc0);
  i32x4 vl1 = *(const i32x4*)(basel + gsrc1);

  for (int kt6 = 0; kt6 < 32; ++kt6) {
    __syncthreads();
    // ---- stage K tile (stride-80 layout) ----
    *(i32x4*)(&sKh[kdst0]) = vh0;
    *(i32x4*)(&sKh[kdst1]) = vh1;
    *(i32x4*)(&sKl[kdst0]) = vl0;
    *(i32x4*)(&sKl[kdst1]) = vl1;
    // ---- V^T scatter: u32 = V[r0][d] | V[r0+16][d]<<16 (2-way free) ----
#pragma unroll
    for (int j = 0; j < 8; ++j) {
      const int w = j >> 1;
      const unsigned a = (unsigned)vh0[w], b = (unsigned)vh1[w];
      const unsigned val = (j & 1) ? ((a >> 16) | (b & 0xffff0000u))
                                   : ((a & 0xffffu) | (b << 16));
      *(unsigned*)(&sVt[vaddr[j]]) = val;
    }
    // ---- prefetch next tile (hides under compute) ----
    const unsigned nb = (unsigned)(((kt6 + 1) & 31) * BK) * ND;
    vh0 = *(const i32x4*)(baseh + nb + gsrc0);
    vh1 = *(const i32x4*)(baseh + nb + gsrc1);
    vl0 = *(const i32x4*)(basel + nb + gsrc0);
    vl1 = *(const i32x4*)(basel + nb + gsrc1);
    __syncthreads();

    // ---- scores S = Qh*Kh + Qh*Kl + Ql*Kh (both q-frags share K reads) ----
    f32x4 acc[2][8];
#pragma unroll
    for (int ks = 0; ks < 8; ++ks) {
      const unsigned koff = koffc + (unsigned)(ks * 16 * KSTR);
      const bf16x8 khf = *(const bf16x8*)(&sKh[koff]);
      const bf16x8 klf = *(const bf16x8*)(&sKl[koff]);
#pragma unroll
      for (int qf = 0; qf < 2; ++qf) {
        f32x4 z = {0.f, 0.f, 0.f, 0.f};
        z = __builtin_amdgcn_mfma_f32_16x16x32_bf16(qh[qf], klf, z, 0, 0, 0);
        z = __builtin_amdgcn_mfma_f32_16x16x32_bf16(ql[qf], khf, z, 0, 0, 0);
        z = __builtin_amdgcn_mfma_f32_16x16x32_bf16(qh[qf], khf, z, 0, 0, 0);
        acc[qf][ks] = z;
      }
    }

    // ---- leaky relu + online softmax + P write (per q-frag) ----
#pragma unroll
    for (int qf = 0; qf < 2; ++qf) {
      float pm[4];
#pragma unroll
      for (int r = 0; r < 4; ++r) pm[r] = -INFINITY;
#pragma unroll
      for (int ks = 0; ks < 8; ++ks)
#pragma unroll
        for (int r = 0; r < 4; ++r) {
          float x = acc[qf][ks][r];
          x = (x > 0.f) ? x : (NEG_SL * x);
          acc[qf][ks][r] = x;
          pm[r] = fmaxf(pm[r], x);
        }
      float sc[4];
#pragma unroll
      for (int r = 0; r < 4; ++r) {
        pm[r] = rmax16(pm[r]);
        const float mn = fmaxf(m_[qf][r], pm[r]);
        sc[r] = __expf(m_[qf][r] - mn);
        m_[qf][r] = mn;
        l_[qf][r] *= sc[r];
      }
      float rs[4];
#pragma unroll
      for (int r = 0; r < 4; ++r) rs[r] = 0.f;
#pragma unroll
      for (int ks = 0; ks < 8; ++ks)
#pragma unroll
        for (int r = 0; r < 4; ++r) {
          const float p = __expf(acc[qf][ks][r] - m_[qf][r]);
          acc[qf][ks][r] = p;
          rs[r] += p;
        }
#pragma unroll
      for (int r = 0; r < 4; ++r) {
        rs[r] = rsum16(rs[r]);
        l_[qf][r] += rs[r];
      }
#pragma unroll
      for (int r = 0; r < 4; ++r) {
        o[qf][0][r] *= sc[r];
        o[qf][1][r] *= sc[r];
      }
      // paired-P write (round-5 verified formula)
#pragma unroll
      for (int r = 0; r < 4; ++r) {
        i32x4 pw;
#pragma unroll
        for (int w = 0; w < 4; ++w)
          pw[w] = (int)pack_bf16_2(acc[qf][2 * w][r], acc[qf][2 * w + 1][r]);
        const int rho = kg * 4 + r;
        const int cb = qr ^ (rho & 7);
        *(i32x4*)(&sP[wid][qf][rho * 256 + cb * 16]) = pw;
      }
    }

    // ---- PV: A = paired P, B = V^T (sigma-matched k-order, b128 reads) ----
#pragma unroll
    for (int qf = 0; qf < 2; ++qf) {
#pragma unroll
      for (int kp = 0; kp < 4; ++kp) {
        const int cbp = (kp * 4 + kg) ^ (qr & 7);
        const bf16x8 pa = *(const bf16x8*)(&sP[wid][qf][qr * 256 + cbp * 16]);
        const int kbR = kp * 4 + kg;
        const int cv = (kbR & 8) | ((kbR + 3 * qr) & 7);
        const bf16x8 vb0 = *(const bf16x8*)(&sVt[qr * VSTR + cv * 16]);
        const bf16x8 vb1 = *(const bf16x8*)(&sVt[(qr + 16) * VSTR + cv * 16]);
        o[qf][0] = __builtin_amdgcn_mfma_f32_16x16x32_bf16(pa, vb0, o[qf][0], 0, 0, 0);
        o[qf][1] = __builtin_amdgcn_mfma_f32_16x16x32_bf16(pa, vb1, o[qf][1], 0, 0, 0);
      }
    }
  }

  // ---- epilogue (round-5 verified, + qf offset) ----
  const int b = bh >> 2, hh = bh & 3;
#pragma unroll
  for (int qf = 0; qf < 2; ++qf)
#pragma unroll
    for (int r = 0; r < 4; ++r) {
      const int q = q0 + qf * 16 + kg * 4 + r;
      const float inv = 1.f / l_[qf][r];
      const size_t rowoff = ((size_t)(b * NN + q)) * 128 + hh * 32;
      out[rowoff + qr] = o[qf][0][r] * inv;
      out[rowoff + 16 + qr] = o[qf][1][r] * inv;
    }
}

extern "C" void kernel_launch(void* const* d_in, const int* in_sizes, int n_in,
                              void* d_out, int out_size, void* d_ws, size_t ws_size,
                              hipStream_t stream) {
  const float* hm = (const float*)d_in[0];
  const float* Wm = (const float*)d_in[1];
  float* out = (float*)d_out;
  ushort* whh = (ushort*)d_ws;
  ushort* whl = whh + (size_t)NB * NH * NN * ND;   // 8 MB total (round-1 proven)

  proj_kernel<<<NB * NN / 64, 256, 0, stream>>>(hm, Wm, whh, whl);
  attn_kernel<<<NB * NH * (NN / BQ), 256, 0, stream>>>(whh, whl, out);
}

// Round 7
// 167.834 us; speedup vs baseline: 1.3980x; 1.0053x over previous
//
#include <hip/hip_runtime.h>

typedef __attribute__((ext_vector_type(8))) short bf16x8;
typedef __attribute__((ext_vector_type(4))) float f32x4;
typedef __attribute__((ext_vector_type(4))) int i32x4;

#define NB 4
#define NN 4096
#define NH 4
#define ND 32
#define NEG_SL 0.2f
#define BQ 128
#define BK 128
#define KSTR 80    // K-tile row stride bytes (64 data + 16 pad)
#define VSTR 272   // sVt row stride bytes (256 data + 16 pad)
#define LOG2E 1.44269504f

static __device__ __forceinline__ ushort f32_to_bf16(float f) {
  unsigned u = __float_as_uint(f);
  unsigned r = 0x7fffu + ((u >> 16) & 1u);
  return (ushort)((u + r) >> 16);
}
static __device__ __forceinline__ float bf16_to_f32(ushort h) {
  return __uint_as_float(((unsigned)h) << 16);
}
// pack two f32 -> one u32 of 2 bf16 (round-half-up); elem0 = a (low half)
static __device__ __forceinline__ unsigned pack_bf16_2(float a, float b) {
  const unsigned ua = (__float_as_uint(a) + 0x8000u) >> 16;
  const unsigned ub = (__float_as_uint(b) + 0x8000u) & 0xffff0000u;
  return ua | ub;
}
static __device__ __forceinline__ bf16x8 as_bf16x8(i32x4 v) {
  union { i32x4 i; bf16x8 b; } u; u.i = v; return u.b;
}
// DPP row_ror-based 16-lane allreduce (VALU pipe)
template <int CTRL>
static __device__ __forceinline__ float row_ror(float x) {
  return __int_as_float(__builtin_amdgcn_update_dpp(
      __float_as_int(x), __float_as_int(x), CTRL, 0xf, 0xf, true));
}
static __device__ __forceinline__ float rmax16(float v) {
  v = fmaxf(v, row_ror<0x121>(v));
  v = fmaxf(v, row_ror<0x122>(v));
  v = fmaxf(v, row_ror<0x124>(v));
  v = fmaxf(v, row_ror<0x128>(v));
  return v;
}
static __device__ __forceinline__ float rsum16(float v) {
  v += row_ror<0x121>(v);
  v += row_ror<0x122>(v);
  v += row_ror<0x124>(v);
  v += row_ror<0x128>(v);
  return v;
}

// ---------------------------------------------------------------------------
// Projection (round-1 proven, byte-identical): Wh = h @ W^T -> hi/lo bf16
// ---------------------------------------------------------------------------
__global__ __launch_bounds__(256) void proj_kernel(const float* __restrict__ hm,
                                                   const float* __restrict__ Wm,
                                                   ushort* __restrict__ whh,
                                                   ushort* __restrict__ whl) {
  __shared__ float sWT[128 * 128];
  __shared__ float sH[64][128];

  const int t = threadIdx.x;
  const long rowbase = (long)blockIdx.x * 64;

  for (int i = t; i < 4096; i += 256) {
    const int o = i & 127, k4 = i >> 7;
    const float4 w = *(const float4*)(Wm + o * 128 + k4 * 4);
    sWT[(k4 * 4 + 0) * 128 + o] = w.x;
    sWT[(k4 * 4 + 1) * 128 + o] = w.y;
    sWT[(k4 * 4 + 2) * 128 + o] = w.z;
    sWT[(k4 * 4 + 3) * 128 + o] = w.w;
  }
  for (int i = t; i < 64 * 128 / 4; i += 256) {
    *((float4*)(&sH[0][0]) + i) = *((const float4*)(hm + rowbase * 128) + i);
  }
  __syncthreads();

  const int oc = (t & 31) * 4;
  const int nr = (t >> 5) * 8;

  float acc[8][4];
#pragma unroll
  for (int r = 0; r < 8; ++r)
#pragma unroll
    for (int j = 0; j < 4; ++j) acc[r][j] = 0.f;

  for (int k = 0; k < 128; ++k) {
    const float4 wv = *(const float4*)(&sWT[k * 128 + oc]);
#pragma unroll
    for (int r = 0; r < 8; ++r) {
      const float hv = sH[nr + r][k];
      acc[r][0] = fmaf(hv, wv.x, acc[r][0]);
      acc[r][1] = fmaf(hv, wv.y, acc[r][1]);
      acc[r][2] = fmaf(hv, wv.z, acc[r][2]);
      acc[r][3] = fmaf(hv, wv.w, acc[r][3]);
    }
  }

  const int hh = oc >> 5;
  const int d0 = oc & 31;
#pragma unroll
  for (int r = 0; r < 8; ++r) {
    const long gn = rowbase + nr + r;
    const long b = gn >> 12;
    const long n = gn & 4095;
    unsigned hi_[4], lo_[4];
#pragma unroll
    for (int j = 0; j < 4; ++j) {
      const float v = acc[r][j];
      const ushort h16 = f32_to_bf16(v);
      hi_[j] = h16;
      lo_[j] = f32_to_bf16(v - bf16_to_f32(h16));
    }
    const size_t idx = (((size_t)(b * NH + hh)) * NN + n) * ND + d0;
    uint2 ph, pl;
    ph.x = hi_[0] | (hi_[1] << 16);
    ph.y = hi_[2] | (hi_[3] << 16);
    pl.x = lo_[0] | (lo_[1] << 16);
    pl.y = lo_[2] | (lo_[3] << 16);
    *(uint2*)(whh + idx) = ph;
    *(uint2*)(whl + idx) = pl;
  }
}

// ---------------------------------------------------------------------------
// Flash attention (round-6 verified structure). Round-7 changes: staging
// thread-map (s=wid, kb/g from lane), Vt block swizzle (kb+3d+2(d>>3))&7,
// K slot swizzle with ^(r>>5), matched score-read ^(ks>>1), exp via exp2+fma.
// All LDS formulas matched write/read pairs; kappa-pairing identical to R6.
// ---------------------------------------------------------------------------
__global__ __launch_bounds__(256) void attn_kernel(const ushort* __restrict__ whh,
                                                   const ushort* __restrict__ whl,
                                                   float* __restrict__ out) {
  __shared__ __align__(16) char sKh[BK * KSTR];     // 10240 B
  __shared__ __align__(16) char sKl[BK * KSTR];     // 10240 B
  __shared__ __align__(16) char sVt[32 * VSTR];     // 8704 B
  __shared__ __align__(16) char sP[4][2][4096];     // 32768 B

  const int t = threadIdx.x;
  const int wid = t >> 6;
  const int lane = t & 63;
  const int qr = lane & 15;
  const int kg = lane >> 4;

  int bid = blockIdx.x;
  bid = (bid & 7) * 64 + (bid >> 3);               // XCD swizzle (512 % 8 == 0)
  const int qt = bid & 31;
  const int bh = bid >> 5;
  const ushort* __restrict__ baseh = whh + (size_t)bh * NN * ND;
  const ushort* __restrict__ basel = whl + (size_t)bh * NN * ND;

  const int q0 = qt * BQ + wid * 32;

  // Q fragments (A-operand): lane holds Q[q0 + qf*16 + qr][kg*8 + j]
  bf16x8 qh[2], ql[2];
#pragma unroll
  for (int qf = 0; qf < 2; ++qf) {
    qh[qf] = *(const bf16x8*)(baseh + (size_t)(q0 + qf * 16 + qr) * ND + kg * 8);
    ql[qf] = *(const bf16x8*)(basel + (size_t)(q0 + qf * 16 + qr) * ND + kg * 8);
  }

  // ---- staging geometry: s = wid (wave-const), (kb, g) from lane ----
  const int kb = lane & 15;
  const int g = lane >> 4;                         // 0..3 varies within wave
  const int s = wid;                               // 16B slot
  const int r0 = g * 32 + kb;                      // rows r0, r0+16
  const unsigned gsrc0 = (unsigned)(r0 * ND + s * 8);
  const unsigned gsrc1 = gsrc0 + 16u * ND;
  const unsigned kdst0 = (unsigned)(r0 * KSTR + ((s ^ (r0 & 3) ^ g) << 4));
  const unsigned kdst1 = kdst0 + 16u * KSTR;
  // V^T scatter addresses: word (d, kb, g), d = s*8+j
  unsigned vaddr[8];
#pragma unroll
  for (int j = 0; j < 8; ++j) {
    const int d = s * 8 + j;
    const int B16 = (kb & 8) | ((kb + 3 * d + 2 * s) & 7);
    vaddr[j] = (unsigned)(d * VSTR + B16 * 16 + g * 4);
  }

  f32x4 o[2][2];
#pragma unroll
  for (int qf = 0; qf < 2; ++qf)
#pragma unroll
    for (int pl = 0; pl < 2; ++pl) o[qf][pl] = f32x4{0.f, 0.f, 0.f, 0.f};
  float m_[2][4], l_[2][4];
#pragma unroll
  for (int qf = 0; qf < 2; ++qf)
#pragma unroll
    for (int r = 0; r < 4; ++r) { m_[qf][r] = -INFINITY; l_[qf][r] = 0.f; }

  // prefetch tile 0 into registers
  i32x4 vh0 = *(const i32x4*)(baseh + gsrc0);
  i32x4 vh1 = *(const i32x4*)(baseh + gsrc1);
  i32x4 vl0 = *(const i32x4*)(basel + gsrc0);
  i32x4 vl1 = *(const i32x4*)(basel + gsrc1);

  for (int kt6 = 0; kt6 < 32; ++kt6) {
    __syncthreads();
    // ---- stage K tile ----
    *(i32x4*)(&sKh[kdst0]) = vh0;
    *(i32x4*)(&sKh[kdst1]) = vh1;
    *(i32x4*)(&sKl[kdst0]) = vl0;
    *(i32x4*)(&sKl[kdst1]) = vl1;
    // ---- V^T scatter: u32 = V[r0][d] | V[r0+16][d]<<16 (2-way = free) ----
#pragma unroll
    for (int j = 0; j < 8; ++j) {
      const int w = j >> 1;
      const unsigned a = (unsigned)vh0[w], b = (unsigned)vh1[w];
      const unsigned val = (j & 1) ? ((a >> 16) | (b & 0xffff0000u))
                                   : ((a & 0xffffu) | (b << 16));
      *(unsigned*)(&sVt[vaddr[j]]) = val;
    }
    // ---- prefetch next tile ----
    const unsigned nb = (unsigned)(((kt6 + 1) & 31) * BK) * ND;
    vh0 = *(const i32x4*)(baseh + nb + gsrc0);
    vh1 = *(const i32x4*)(baseh + nb + gsrc1);
    vl0 = *(const i32x4*)(basel + nb + gsrc0);
    vl1 = *(const i32x4*)(basel + nb + gsrc1);
    __syncthreads();

    // ---- scores S = Qh*Kh + Qh*Kl + Ql*Kh ----
    f32x4 acc[2][8];
#pragma unroll
    for (int ks = 0; ks < 8; ++ks) {
      const unsigned koff = (unsigned)((ks * 16 + qr) * KSTR) +
                            (unsigned)(((kg ^ (qr & 3) ^ (ks >> 1)) << 4));
      const bf16x8 khf = *(const bf16x8*)(&sKh[koff]);
      const bf16x8 klf = *(const bf16x8*)(&sKl[koff]);
#pragma unroll
      for (int qf = 0; qf < 2; ++qf) {
        f32x4 z = {0.f, 0.f, 0.f, 0.f};
        z = __builtin_amdgcn_mfma_f32_16x16x32_bf16(qh[qf], klf, z, 0, 0, 0);
        z = __builtin_amdgcn_mfma_f32_16x16x32_bf16(ql[qf], khf, z, 0, 0, 0);
        z = __builtin_amdgcn_mfma_f32_16x16x32_bf16(qh[qf], khf, z, 0, 0, 0);
        acc[qf][ks] = z;
      }
    }

    // ---- leaky relu + online softmax + P write (per q-frag) ----
#pragma unroll
    for (int qf = 0; qf < 2; ++qf) {
      float pm[4];
#pragma unroll
      for (int r = 0; r < 4; ++r) pm[r] = -INFINITY;
#pragma unroll
      for (int ks = 0; ks < 8; ++ks)
#pragma unroll
        for (int r = 0; r < 4; ++r) {
          float x = acc[qf][ks][r];
          x = (x > 0.f) ? x : (NEG_SL * x);
          acc[qf][ks][r] = x;
          pm[r] = fmaxf(pm[r], x);
        }
      float sc[4], nm[4];
#pragma unroll
      for (int r = 0; r < 4; ++r) {
        pm[r] = rmax16(pm[r]);
        const float mn = fmaxf(m_[qf][r], pm[r]);
        sc[r] = __expf(m_[qf][r] - mn);
        m_[qf][r] = mn;
        nm[r] = -mn * LOG2E;
        l_[qf][r] *= sc[r];
      }
      float rs[4];
#pragma unroll
      for (int r = 0; r < 4; ++r) rs[r] = 0.f;
#pragma unroll
      for (int ks = 0; ks < 8; ++ks)
#pragma unroll
        for (int r = 0; r < 4; ++r) {
          const float p = __builtin_amdgcn_exp2f(fmaf(acc[qf][ks][r], LOG2E, nm[r]));
          acc[qf][ks][r] = p;
          rs[r] += p;
        }
#pragma unroll
      for (int r = 0; r < 4; ++r) {
        rs[r] = rsum16(rs[r]);
        l_[qf][r] += rs[r];
      }
#pragma unroll
      for (int r = 0; r < 4; ++r) {
        o[qf][0][r] *= sc[r];
        o[qf][1][r] *= sc[r];
      }
      // paired-P write (round-5/6 verified formula)
#pragma unroll
      for (int r = 0; r < 4; ++r) {
        i32x4 pw;
#pragma unroll
        for (int w = 0; w < 4; ++w)
          pw[w] = (int)pack_bf16_2(acc[qf][2 * w][r], acc[qf][2 * w + 1][r]);
        const int rho = kg * 4 + r;
        const int cb = qr ^ (rho & 7);
        *(i32x4*)(&sP[wid][qf][rho * 256 + cb * 16]) = pw;
      }
    }

    // ---- PV: A = paired P, B = V^T (kappa-matched, b128 reads) ----
#pragma unroll
    for (int kp = 0; kp < 4; ++kp) {
      const int kbR = kp * 4 + kg;
      const int cin = kbR + 3 * qr + 2 * (qr >> 3);
      const int cv0 = (kbR & 8) | (cin & 7);
      const int cv1 = (kbR & 8) | ((cin + 4) & 7);
      const bf16x8 vb0 = *(const bf16x8*)(&sVt[qr * VSTR + cv0 * 16]);
      const bf16x8 vb1 = *(const bf16x8*)(&sVt[(qr + 16) * VSTR + cv1 * 16]);
      const int cbp = kbR ^ (qr & 7);
#pragma unroll
      for (int qf = 0; qf < 2; ++qf) {
        const bf16x8 pa = *(const bf16x8*)(&sP[wid][qf][qr * 256 + cbp * 16]);
        o[qf][0] = __builtin_amdgcn_mfma_f32_16x16x32_bf16(pa, vb0, o[qf][0], 0, 0, 0);
        o[qf][1] = __builtin_amdgcn_mfma_f32_16x16x32_bf16(pa, vb1, o[qf][1], 0, 0, 0);
      }
    }
  }

  // ---- epilogue (verified) ----
  const int b = bh >> 2, hh = bh & 3;
#pragma unroll
  for (int qf = 0; qf < 2; ++qf)
#pragma unroll
    for (int r = 0; r < 4; ++r) {
      const int q = q0 + qf * 16 + kg * 4 + r;
      const float inv = 1.f / l_[qf][r];
      const size_t rowoff = ((size_t)(b * NN + q)) * 128 + hh * 32;
      out[rowoff + qr] = o[qf][0][r] * inv;
      out[rowoff + 16 + qr] = o[qf][1][r] * inv;
    }
}

extern "C" void kernel_launch(void* const* d_in, const int* in_sizes, int n_in,
                              void* d_out, int out_size, void* d_ws, size_t ws_size,
                              hipStream_t stream) {
  const float* hm = (const float*)d_in[0];
  const float* Wm = (const float*)d_in[1];
  float* out = (float*)d_out;
  ushort* whh = (ushort*)d_ws;
  ushort* whl = whh + (size_t)NB * NH * NN * ND;   // 8 MB total (proven)

  proj_kernel<<<NB * NN / 64, 256, 0, stream>>>(hm, Wm, whh, whl);
  attn_kernel<<<NB * NH * (NN / BQ), 256, 0, stream>>>(whh, whl, out);
}

// Round 8
// 160.224 us; speedup vs baseline: 1.4644x; 1.0475x over previous
//
#include <hip/hip_runtime.h>

typedef __attribute__((ext_vector_type(8))) short bf16x8;
typedef __attribute__((ext_vector_type(4))) float f32x4;
typedef __attribute__((ext_vector_type(4))) int i32x4;

#define NB 4
#define NN 4096
#define NH 4
#define ND 32
#define NEG_SL 0.2f
#define BQ 64
#define BK 128
#define KSTR 80    // K-tile row stride bytes (64 data + 16 pad)
#define VSTR 272   // sVt row stride bytes (256 data + 16 pad)
#define CSC 1.2011224f   // sqrt(log2(e)); Wh scaled by this -> scores in exp2 units

static __device__ __forceinline__ ushort f32_to_bf16(float f) {
  unsigned u = __float_as_uint(f);
  unsigned r = 0x7fffu + ((u >> 16) & 1u);
  return (ushort)((u + r) >> 16);
}
static __device__ __forceinline__ float bf16_to_f32(ushort h) {
  return __uint_as_float(((unsigned)h) << 16);
}
// v_cvt_pk_bf16_f32: dst = {lo: bf16(a), hi: bf16(b)} (T12-verified order)
static __device__ __forceinline__ unsigned cvt_pk_bf16(float a, float b) {
  unsigned d;
  asm("v_cvt_pk_bf16_f32 %0, %1, %2" : "=v"(d) : "v"(a), "v"(b));
  return d;
}
static __device__ __forceinline__ bf16x8 as_bf16x8(i32x4 v) {
  union { i32x4 i; bf16x8 b; } u; u.i = v; return u.b;
}
// DPP row_ror-based 16-lane allreduce (VALU pipe)
template <int CTRL>
static __device__ __forceinline__ float row_ror(float x) {
  return __int_as_float(__builtin_amdgcn_update_dpp(
      __float_as_int(x), __float_as_int(x), CTRL, 0xf, 0xf, true));
}
static __device__ __forceinline__ float rmax16(float v) {
  v = fmaxf(v, row_ror<0x121>(v));
  v = fmaxf(v, row_ror<0x122>(v));
  v = fmaxf(v, row_ror<0x124>(v));
  v = fmaxf(v, row_ror<0x128>(v));
  return v;
}
static __device__ __forceinline__ float rsum16(float v) {
  v += row_ror<0x121>(v);
  v += row_ror<0x122>(v);
  v += row_ror<0x124>(v);
  v += row_ror<0x128>(v);
  return v;
}

// ---------------------------------------------------------------------------
// Projection: Wh = (h @ W^T) * CSC -> hi/lo bf16 (scores come out in exp2
// units: Q.K * CSC^2 = e * log2e). V is also scaled; epilogue divides.
// ---------------------------------------------------------------------------
__global__ __launch_bounds__(256) void proj_kernel(const float* __restrict__ hm,
                                                   const float* __restrict__ Wm,
                                                   ushort* __restrict__ whh,
                                                   ushort* __restrict__ whl) {
  __shared__ float sWT[128 * 128];
  __shared__ float sH[64][128];

  const int t = threadIdx.x;
  const long rowbase = (long)blockIdx.x * 64;

  for (int i = t; i < 4096; i += 256) {
    const int o = i & 127, k4 = i >> 7;
    const float4 w = *(const float4*)(Wm + o * 128 + k4 * 4);
    sWT[(k4 * 4 + 0) * 128 + o] = w.x;
    sWT[(k4 * 4 + 1) * 128 + o] = w.y;
    sWT[(k4 * 4 + 2) * 128 + o] = w.z;
    sWT[(k4 * 4 + 3) * 128 + o] = w.w;
  }
  for (int i = t; i < 64 * 128 / 4; i += 256) {
    *((float4*)(&sH[0][0]) + i) = *((const float4*)(hm + rowbase * 128) + i);
  }
  __syncthreads();

  const int oc = (t & 31) * 4;
  const int nr = (t >> 5) * 8;

  float acc[8][4];
#pragma unroll
  for (int r = 0; r < 8; ++r)
#pragma unroll
    for (int j = 0; j < 4; ++j) acc[r][j] = 0.f;

  for (int k = 0; k < 128; ++k) {
    const float4 wv = *(const float4*)(&sWT[k * 128 + oc]);
#pragma unroll
    for (int r = 0; r < 8; ++r) {
      const float hv = sH[nr + r][k];
      acc[r][0] = fmaf(hv, wv.x, acc[r][0]);
      acc[r][1] = fmaf(hv, wv.y, acc[r][1]);
      acc[r][2] = fmaf(hv, wv.z, acc[r][2]);
      acc[r][3] = fmaf(hv, wv.w, acc[r][3]);
    }
  }

  const int hh = oc >> 5;
  const int d0 = oc & 31;
#pragma unroll
  for (int r = 0; r < 8; ++r) {
    const long gn = rowbase + nr + r;
    const long b = gn >> 12;
    const long n = gn & 4095;
    unsigned hi_[4], lo_[4];
#pragma unroll
    for (int j = 0; j < 4; ++j) {
      const float v = acc[r][j] * CSC;
      const ushort h16 = f32_to_bf16(v);
      hi_[j] = h16;
      lo_[j] = f32_to_bf16(v - bf16_to_f32(h16));
    }
    const size_t idx = (((size_t)(b * NH + hh)) * NN + n) * ND + d0;
    uint2 ph, pl;
    ph.x = hi_[0] | (hi_[1] << 16);
    ph.y = hi_[2] | (hi_[3] << 16);
    pl.x = lo_[0] | (lo_[1] << 16);
    pl.y = lo_[2] | (lo_[3] << 16);
    *(uint2*)(whh + idx) = ph;
    *(uint2*)(whl + idx) = pl;
  }
}

// ---------------------------------------------------------------------------
// Flash attention. R8: BQ=64 (1 q-frag/wave, R5-proven shape), sP halved ->
// 45.6 KB LDS -> 3 blocks/CU; cvt_pk P-pack fused into exp loop; exp2-unit
// softmax (no per-element fma). All LDS formulas byte-identical to R7.
// ---------------------------------------------------------------------------
__global__ __launch_bounds__(256, 3) void attn_kernel(const ushort* __restrict__ whh,
                                                      const ushort* __restrict__ whl,
                                                      float* __restrict__ out) {
  __shared__ __align__(16) char sKh[BK * KSTR];     // 10240 B
  __shared__ __align__(16) char sKl[BK * KSTR];     // 10240 B
  __shared__ __align__(16) char sVt[32 * VSTR];     // 8704 B
  __shared__ __align__(16) char sP[4][4096];        // 16384 B  (total 45568 B)

  const int t = threadIdx.x;
  const int wid = t >> 6;
  const int lane = t & 63;
  const int qr = lane & 15;
  const int kg = lane >> 4;

  int bid = blockIdx.x;
  bid = (bid & 7) * 128 + (bid >> 3);              // XCD swizzle (1024 % 8 == 0)
  const int qt = bid & 63;
  const int bh = bid >> 6;
  const ushort* __restrict__ baseh = whh + (size_t)bh * NN * ND;
  const ushort* __restrict__ basel = whl + (size_t)bh * NN * ND;

  const int q0 = qt * BQ + wid * 16;

  // Q fragment (A-operand): lane holds Q[q0 + qr][kg*8 + j]
  const bf16x8 qh = *(const bf16x8*)(baseh + (size_t)(q0 + qr) * ND + kg * 8);
  const bf16x8 ql = *(const bf16x8*)(basel + (size_t)(q0 + qr) * ND + kg * 8);

  // ---- staging geometry (R7-proven): s = wid, (kb, g) from lane ----
  const int kb = lane & 15;
  const int g = lane >> 4;
  const int s = wid;
  const int r0 = g * 32 + kb;                      // rows r0, r0+16
  const unsigned gsrc0 = (unsigned)(r0 * ND + s * 8);
  const unsigned gsrc1 = gsrc0 + 16u * ND;
  const unsigned kdst0 = (unsigned)(r0 * KSTR + ((s ^ (r0 & 3) ^ g) << 4));
  const unsigned kdst1 = kdst0 + 16u * KSTR;
  unsigned vaddr[8];
#pragma unroll
  for (int j = 0; j < 8; ++j) {
    const int d = s * 8 + j;
    const int B16 = (kb & 8) | ((kb + 3 * d + 2 * s) & 7);
    vaddr[j] = (unsigned)(d * VSTR + B16 * 16 + g * 4);
  }

  f32x4 o0 = {0.f, 0.f, 0.f, 0.f};
  f32x4 o1 = {0.f, 0.f, 0.f, 0.f};
  float m_[4], l_[4];
#pragma unroll
  for (int r = 0; r < 4; ++r) { m_[r] = -INFINITY; l_[r] = 0.f; }

  // prefetch tile 0 into registers
  i32x4 vh0 = *(const i32x4*)(baseh + gsrc0);
  i32x4 vh1 = *(const i32x4*)(baseh + gsrc1);
  i32x4 vl0 = *(const i32x4*)(basel + gsrc0);
  i32x4 vl1 = *(const i32x4*)(basel + gsrc1);

  for (int kt6 = 0; kt6 < 32; ++kt6) {
    __syncthreads();
    // ---- stage K tile (R7 layout) ----
    *(i32x4*)(&sKh[kdst0]) = vh0;
    *(i32x4*)(&sKh[kdst1]) = vh1;
    *(i32x4*)(&sKl[kdst0]) = vl0;
    *(i32x4*)(&sKl[kdst1]) = vl1;
    // ---- V^T scatter (R7 layout): u32 = V[r0][d] | V[r0+16][d]<<16 ----
#pragma unroll
    for (int j = 0; j < 8; ++j) {
      const int w = j >> 1;
      const unsigned a = (unsigned)vh0[w], b = (unsigned)vh1[w];
      const unsigned val = (j & 1) ? ((a >> 16) | (b & 0xffff0000u))
                                   : ((a & 0xffffu) | (b << 16));
      *(unsigned*)(&sVt[vaddr[j]]) = val;
    }
    // ---- prefetch next tile ----
    const unsigned nb = (unsigned)(((kt6 + 1) & 31) * BK) * ND;
    vh0 = *(const i32x4*)(baseh + nb + gsrc0);
    vh1 = *(const i32x4*)(baseh + nb + gsrc1);
    vl0 = *(const i32x4*)(basel + nb + gsrc0);
    vl1 = *(const i32x4*)(basel + nb + gsrc1);
    __syncthreads();

    // ---- scores S = Qh*Kh + Qh*Kl + Ql*Kh (R7-proven read formula) ----
    f32x4 acc[8];
#pragma unroll
    for (int ks = 0; ks < 8; ++ks) {
      const unsigned koff = (unsigned)((ks * 16 + qr) * KSTR) +
                            (unsigned)(((kg ^ (qr & 3) ^ (ks >> 1)) << 4));
      const bf16x8 khf = *(const bf16x8*)(&sKh[koff]);
      const bf16x8 klf = *(const bf16x8*)(&sKl[koff]);
      f32x4 z = {0.f, 0.f, 0.f, 0.f};
      z = __builtin_amdgcn_mfma_f32_16x16x32_bf16(qh, klf, z, 0, 0, 0);
      z = __builtin_amdgcn_mfma_f32_16x16x32_bf16(ql, khf, z, 0, 0, 0);
      z = __builtin_amdgcn_mfma_f32_16x16x32_bf16(qh, khf, z, 0, 0, 0);
      acc[ks] = z;
    }

    // ---- leaky relu + row max (scores already in exp2 units) ----
    float pm[4];
#pragma unroll
    for (int r = 0; r < 4; ++r) pm[r] = -INFINITY;
#pragma unroll
    for (int ks = 0; ks < 8; ++ks)
#pragma unroll
      for (int r = 0; r < 4; ++r) {
        float x = acc[ks][r];
        x = fmaxf(x, NEG_SL * x);
        acc[ks][r] = x;
        pm[r] = fmaxf(pm[r], x);
      }
    float sc[4];
#pragma unroll
    for (int r = 0; r < 4; ++r) {
      pm[r] = rmax16(pm[r]);
      const float mn = fmaxf(m_[r], pm[r]);
      sc[r] = __builtin_amdgcn_exp2f(m_[r] - mn);   // exact in exp2 units
      m_[r] = mn;
      l_[r] *= sc[r];
    }
#pragma unroll
    for (int r = 0; r < 4; ++r) { o0[r] *= sc[r]; o1[r] *= sc[r]; }

    // ---- p = exp2(x - m): sum + cvt_pk pack fused; write paired P ----
#pragma unroll
    for (int r = 0; r < 4; ++r) {
      i32x4 pw;
      float rs = 0.f;
#pragma unroll
      for (int w = 0; w < 4; ++w) {
        const float p0 = __builtin_amdgcn_exp2f(acc[2 * w][r] - m_[r]);
        const float p1 = __builtin_amdgcn_exp2f(acc[2 * w + 1][r] - m_[r]);
        rs += p0 + p1;
        pw[w] = (int)cvt_pk_bf16(p0, p1);
      }
      l_[r] += rsum16(rs);
      const int rho = kg * 4 + r;
      const int cb = qr ^ (rho & 7);
      *(i32x4*)(&sP[wid][rho * 256 + cb * 16]) = pw;
    }

    // ---- PV: A = paired P, B = V^T (R7-proven read formulas) ----
#pragma unroll
    for (int kp = 0; kp < 4; ++kp) {
      const int kbR = kp * 4 + kg;
      const int cin = kbR + 3 * qr + 2 * (qr >> 3);
      const int cv0 = (kbR & 8) | (cin & 7);
      const int cv1 = (kbR & 8) | ((cin + 4) & 7);
      const bf16x8 vb0 = *(const bf16x8*)(&sVt[qr * VSTR + cv0 * 16]);
      const bf16x8 vb1 = *(const bf16x8*)(&sVt[(qr + 16) * VSTR + cv1 * 16]);
      const int cbp = kbR ^ (qr & 7);
      const bf16x8 pa = *(const bf16x8*)(&sP[wid][qr * 256 + cbp * 16]);
      o0 = __builtin_amdgcn_mfma_f32_16x16x32_bf16(pa, vb0, o0, 0, 0, 0);
      o1 = __builtin_amdgcn_mfma_f32_16x16x32_bf16(pa, vb1, o1, 0, 0, 0);
    }
  }

  // ---- epilogue: out = o / (CSC * l)  (V was scaled by CSC) ----
  const int b = bh >> 2, hh = bh & 3;
#pragma unroll
  for (int r = 0; r < 4; ++r) {
    const int q = q0 + kg * 4 + r;
    const float inv = 1.f / (CSC * l_[r]);
    const size_t rowoff = ((size_t)(b * NN + q)) * 128 + hh * 32;
    out[rowoff + qr] = o0[r] * inv;
    out[rowoff + 16 + qr] = o1[r] * inv;
  }
}

extern "C" void kernel_launch(void* const* d_in, const int* in_sizes, int n_in,
                              void* d_out, int out_size, void* d_ws, size_t ws_size,
                              hipStream_t stream) {
  const float* hm = (const float*)d_in[0];
  const float* Wm = (const float*)d_in[1];
  float* out = (float*)d_out;
  ushort* whh = (ushort*)d_ws;
  ushort* whl = whh + (size_t)NB * NH * NN * ND;   // 8 MB total (proven)

  proj_kernel<<<NB * NN / 64, 256, 0, stream>>>(hm, Wm, whh, whl);
  attn_kernel<<<NB * NH * (NN / BQ), 256, 0, stream>>>(whh, whl, out);
}

// Round 13
// 134.366 us; speedup vs baseline: 1.7463x; 1.1924x over previous
//
#include <hip/hip_runtime.h>

typedef __attribute__((ext_vector_type(8))) _Float16 f16x8;
typedef __attribute__((ext_vector_type(2))) __fp16 fp16x2;
typedef __attribute__((ext_vector_type(4))) float f32x4;
typedef __attribute__((ext_vector_type(4))) int i32x4;

#define NB 4
#define NN 4096
#define NH 4
#define ND 32
#define NEG_SL 0.2f
#define BQ 64
#define BK 128
#define KSTR 80    // K-tile row stride bytes (R8-proven)
#define VSTR 272   // sVt row stride bytes (R8-proven)
#define CSC 1.2011224f   // sqrt(log2(e)); Wh scaled -> scores in exp2 units

static __device__ __forceinline__ ushort f32_to_f16u(float f) {
  union { _Float16 h; ushort u; } c;
  c.h = (_Float16)f;
  return c.u;
}
static __device__ __forceinline__ float f16u_to_f32(ushort u) {
  union { _Float16 h; ushort u; } c;
  c.u = u;
  return (float)c.h;
}
// v_cvt_pkrtz_f16_f32: dst = {lo: f16(a), hi: f16(b)}
static __device__ __forceinline__ unsigned cvt_pk_f16(float a, float b) {
  union { fp16x2 h; unsigned u; } c;
  c.h = __builtin_amdgcn_cvt_pkrtz(a, b);
  return c.u;
}
// DPP row_ror-based 16-lane allreduce (VALU pipe)
template <int CTRL>
static __device__ __forceinline__ float row_ror(float x) {
  return __int_as_float(__builtin_amdgcn_update_dpp(
      __float_as_int(x), __float_as_int(x), CTRL, 0xf, 0xf, true));
}
static __device__ __forceinline__ float rmax16(float v) {
  v = fmaxf(v, row_ror<0x121>(v));
  v = fmaxf(v, row_ror<0x122>(v));
  v = fmaxf(v, row_ror<0x124>(v));
  v = fmaxf(v, row_ror<0x128>(v));
  return v;
}
static __device__ __forceinline__ float rsum16(float v) {
  v += row_ror<0x121>(v);
  v += row_ror<0x122>(v);
  v += row_ror<0x124>(v);
  v += row_ror<0x128>(v);
  return v;
}

// ---------------------------------------------------------------------------
// Projection: Wh = (h @ W^T) * CSC -> f16 hi plane + f16 residual plane.
// ---------------------------------------------------------------------------
__global__ __launch_bounds__(256) void proj_kernel(const float* __restrict__ hm,
                                                   const float* __restrict__ Wm,
                                                   ushort* __restrict__ whh,
                                                   ushort* __restrict__ whl) {
  __shared__ float sWT[128 * 128];
  __shared__ float sH[64][128];

  const int t = threadIdx.x;
  const long rowbase = (long)blockIdx.x * 64;

  for (int i = t; i < 4096; i += 256) {
    const int o = i & 127, k4 = i >> 7;
    const float4 w = *(const float4*)(Wm + o * 128 + k4 * 4);
    sWT[(k4 * 4 + 0) * 128 + o] = w.x;
    sWT[(k4 * 4 + 1) * 128 + o] = w.y;
    sWT[(k4 * 4 + 2) * 128 + o] = w.z;
    sWT[(k4 * 4 + 3) * 128 + o] = w.w;
  }
  for (int i = t; i < 64 * 128 / 4; i += 256) {
    *((float4*)(&sH[0][0]) + i) = *((const float4*)(hm + rowbase * 128) + i);
  }
  __syncthreads();

  const int oc = (t & 31) * 4;
  const int nr = (t >> 5) * 8;

  float acc[8][4];
#pragma unroll
  for (int r = 0; r < 8; ++r)
#pragma unroll
    for (int j = 0; j < 4; ++j) acc[r][j] = 0.f;

  for (int k = 0; k < 128; ++k) {
    const float4 wv = *(const float4*)(&sWT[k * 128 + oc]);
#pragma unroll
    for (int r = 0; r < 8; ++r) {
      const float hv = sH[nr + r][k];
      acc[r][0] = fmaf(hv, wv.x, acc[r][0]);
      acc[r][1] = fmaf(hv, wv.y, acc[r][1]);
      acc[r][2] = fmaf(hv, wv.z, acc[r][2]);
      acc[r][3] = fmaf(hv, wv.w, acc[r][3]);
    }
  }

  const int hh = oc >> 5;
  const int d0 = oc & 31;
#pragma unroll
  for (int r = 0; r < 8; ++r) {
    const long gn = rowbase + nr + r;
    const long b = gn >> 12;
    const long n = gn & 4095;
    unsigned hi_[4], lo_[4];
#pragma unroll
    for (int j = 0; j < 4; ++j) {
      const float v = acc[r][j] * CSC;
      const ushort h16 = f32_to_f16u(v);
      hi_[j] = h16;
      lo_[j] = f32_to_f16u(v - f16u_to_f32(h16));
    }
    const size_t idx = (((size_t)(b * NH + hh)) * NN + n) * ND + d0;
    uint2 ph, pl;
    ph.x = hi_[0] | (hi_[1] << 16);
    ph.y = hi_[2] | (hi_[3] << 16);
    pl.x = lo_[0] | (lo_[1] << 16);
    pl.y = lo_[2] | (lo_[3] << 16);
    *(uint2*)(whh + idx) = ph;
    *(uint2*)(whl + idx) = pl;
  }
}

// ---------------------------------------------------------------------------
// Flash attention, f16. R13 = R12 with the cvt_pkrtz type fix. R8 structure
// and address formulas verbatim; single f16 K plane; Q hi/lo in registers
// (2-MFMA scores); f16 PV; LDS 43520 -> 3 blocks/CU (proven-safe regime).
// ---------------------------------------------------------------------------
__global__ __launch_bounds__(256, 3) void attn_kernel(const ushort* __restrict__ whh,
                                                      const ushort* __restrict__ whl,
                                                      float* __restrict__ out) {
  __shared__ __align__(16) char sK[BK * KSTR];      // 10240 B
  __shared__ __align__(16) char sVt[32 * VSTR];     // 8704 B
  __shared__ __align__(16) char sP[4][6144];        // 24576 B (4096 used + pad)
                                                    // total 43520 B -> 3 blk/CU

  const int t = threadIdx.x;
  const int wid = t >> 6;
  const int lane = t & 63;
  const int qr = lane & 15;
  const int kg = lane >> 4;

  int bid = blockIdx.x;
  bid = (bid & 7) * 128 + (bid >> 3);              // XCD swizzle (1024 % 8 == 0)
  const int qt = bid & 63;
  const int bh = bid >> 6;
  const ushort* __restrict__ baseh = whh + (size_t)bh * NN * ND;
  const ushort* __restrict__ basel = whl + (size_t)bh * NN * ND;

  const int q0 = qt * BQ + wid * 16;

  // Q fragments (A-operand), hi/lo f16: lane holds Q[q0 + qr][kg*8 + j]
  const f16x8 qh = *(const f16x8*)(baseh + (size_t)(q0 + qr) * ND + kg * 8);
  const f16x8 ql = *(const f16x8*)(basel + (size_t)(q0 + qr) * ND + kg * 8);

  // ---- staging geometry (R8-exact): s = wid, (kb, g) from lane ----
  const int kb = lane & 15;
  const int g = lane >> 4;
  const int s = wid;
  const int r0 = g * 32 + kb;                      // rows r0, r0+16
  const unsigned gsrc0 = (unsigned)(r0 * ND + s * 8);
  const unsigned gsrc1 = gsrc0 + 16u * ND;
  const unsigned kdst0 = (unsigned)(r0 * KSTR + ((s ^ (r0 & 3) ^ g) << 4));
  const unsigned kdst1 = kdst0 + 16u * KSTR;
  unsigned vaddr[8];
#pragma unroll
  for (int j = 0; j < 8; ++j) {
    const int d = s * 8 + j;
    const int B16 = (kb & 8) | ((kb + 3 * d + 2 * s) & 7);
    vaddr[j] = (unsigned)(d * VSTR + B16 * 16 + g * 4);
  }

  f32x4 o0 = {0.f, 0.f, 0.f, 0.f};
  f32x4 o1 = {0.f, 0.f, 0.f, 0.f};
  float m_[4], l_[4];
#pragma unroll
  for (int r = 0; r < 4; ++r) { m_[r] = -INFINITY; l_[r] = 0.f; }

  // prefetch tile 0 into registers (hi plane only)
  i32x4 vh0 = *(const i32x4*)(baseh + gsrc0);
  i32x4 vh1 = *(const i32x4*)(baseh + gsrc1);

  for (int kt6 = 0; kt6 < 32; ++kt6) {
    __syncthreads();
    // ---- stage K tile (R8 layout, single plane) ----
    *(i32x4*)(&sK[kdst0]) = vh0;
    *(i32x4*)(&sK[kdst1]) = vh1;
    // ---- V^T scatter (R8 layout): u32 = V[r0][d] | V[r0+16][d]<<16 ----
#pragma unroll
    for (int j = 0; j < 8; ++j) {
      const int w = j >> 1;
      const unsigned a = (unsigned)vh0[w], b = (unsigned)vh1[w];
      const unsigned val = (j & 1) ? ((a >> 16) | (b & 0xffff0000u))
                                   : ((a & 0xffffu) | (b << 16));
      *(unsigned*)(&sVt[vaddr[j]]) = val;
    }
    // ---- prefetch next tile ----
    const unsigned nb = (unsigned)(((kt6 + 1) & 31) * BK) * ND;
    vh0 = *(const i32x4*)(baseh + nb + gsrc0);
    vh1 = *(const i32x4*)(baseh + nb + gsrc1);
    __syncthreads();

    // ---- scores S = Qh*K + Ql*K  (Q 22-bit effective, K f16) ----
    f32x4 acc[8];
#pragma unroll
    for (int ks = 0; ks < 8; ++ks) {
      const unsigned koff = (unsigned)((ks * 16 + qr) * KSTR) +
                            (unsigned)(((kg ^ (qr & 3) ^ (ks >> 1)) << 4));
      const f16x8 khf = *(const f16x8*)(&sK[koff]);
      f32x4 z = {0.f, 0.f, 0.f, 0.f};
      z = __builtin_amdgcn_mfma_f32_16x16x32_f16(ql, khf, z, 0, 0, 0);
      z = __builtin_amdgcn_mfma_f32_16x16x32_f16(qh, khf, z, 0, 0, 0);
      acc[ks] = z;
    }

    // ---- leaky relu + row max (scores in exp2 units) ----
    float pm[4];
#pragma unroll
    for (int r = 0; r < 4; ++r) pm[r] = -INFINITY;
#pragma unroll
    for (int ks = 0; ks < 8; ++ks)
#pragma unroll
      for (int r = 0; r < 4; ++r) {
        float x = acc[ks][r];
        x = fmaxf(x, NEG_SL * x);
        acc[ks][r] = x;
        pm[r] = fmaxf(pm[r], x);
      }
    float sc[4];
#pragma unroll
    for (int r = 0; r < 4; ++r) {
      pm[r] = rmax16(pm[r]);
      const float mn = fmaxf(m_[r], pm[r]);
      sc[r] = __builtin_amdgcn_exp2f(m_[r] - mn);
      m_[r] = mn;
      l_[r] *= sc[r];
    }
#pragma unroll
    for (int r = 0; r < 4; ++r) { o0[r] *= sc[r]; o1[r] *= sc[r]; }

    // ---- p = exp2(x - m): sum + pkrtz pack fused; write paired P ----
#pragma unroll
    for (int r = 0; r < 4; ++r) {
      i32x4 pw;
      float rs = 0.f;
#pragma unroll
      for (int w = 0; w < 4; ++w) {
        const float p0 = __builtin_amdgcn_exp2f(acc[2 * w][r] - m_[r]);
        const float p1 = __builtin_amdgcn_exp2f(acc[2 * w + 1][r] - m_[r]);
        rs += p0 + p1;
        pw[w] = (int)cvt_pk_f16(p0, p1);
      }
      l_[r] += rsum16(rs);
      const int rho = kg * 4 + r;
      const int cb = qr ^ (rho & 7);
      *(i32x4*)(&sP[wid][rho * 256 + cb * 16]) = pw;
    }

    // ---- PV: A = paired P, B = V^T (R8-exact read formulas), f16 ----
#pragma unroll
    for (int kp = 0; kp < 4; ++kp) {
      const int kbR = kp * 4 + kg;
      const int cin = kbR + 3 * qr + 2 * (qr >> 3);
      const int cv0 = (kbR & 8) | (cin & 7);
      const int cv1 = (kbR & 8) | ((cin + 4) & 7);
      const f16x8 vb0 = *(const f16x8*)(&sVt[qr * VSTR + cv0 * 16]);
      const f16x8 vb1 = *(const f16x8*)(&sVt[(qr + 16) * VSTR + cv1 * 16]);
      const int cbp = kbR ^ (qr & 7);
      const f16x8 pa = *(const f16x8*)(&sP[wid][qr * 256 + cbp * 16]);
      o0 = __builtin_amdgcn_mfma_f32_16x16x32_f16(pa, vb0, o0, 0, 0, 0);
      o1 = __builtin_amdgcn_mfma_f32_16x16x32_f16(pa, vb1, o1, 0, 0, 0);
    }
  }

  // ---- epilogue: out = o / (CSC * l)  (V was scaled by CSC) ----
  const int b = bh >> 2, hh = bh & 3;
#pragma unroll
  for (int r = 0; r < 4; ++r) {
    const int q = q0 + kg * 4 + r;
    const float inv = 1.f / (CSC * l_[r]);
    const size_t rowoff = ((size_t)(b * NN + q)) * 128 + hh * 32;
    out[rowoff + qr] = o0[r] * inv;
    out[rowoff + 16 + qr] = o1[r] * inv;
  }
}

extern "C" void kernel_launch(void* const* d_in, const int* in_sizes, int n_in,
                              void* d_out, int out_size, void* d_ws, size_t ws_size,
                              hipStream_t stream) {
  const float* hm = (const float*)d_in[0];
  const float* Wm = (const float*)d_in[1];
  float* out = (float*)d_out;
  ushort* whh = (ushort*)d_ws;
  ushort* whl = whh + (size_t)NB * NH * NN * ND;   // 8 MB total (proven)

  proj_kernel<<<NB * NN / 64, 256, 0, stream>>>(hm, Wm, whh, whl);
  attn_kernel<<<NB * NH * (NN / BQ), 256, 0, stream>>>(whh, whl, out);
}

// Round 14
// 126.883 us; speedup vs baseline: 1.8493x; 1.0590x over previous
//
#include <hip/hip_runtime.h>

typedef __attribute__((ext_vector_type(8))) _Float16 f16x8;
typedef __attribute__((ext_vector_type(2))) __fp16 fp16x2;
typedef __attribute__((ext_vector_type(4))) float f32x4;
typedef __attribute__((ext_vector_type(4))) int i32x4;

#define NB 4
#define NN 4096
#define NH 4
#define ND 32
#define NEG_SL 0.2f
#define BQ 64
#define BK 128
#define KSTR 80    // K-tile row stride bytes (R8-proven)
#define VSTR 272   // sVt row stride bytes (R8-proven)
#define CSC 1.2011224f   // sqrt(log2(e)); Wh scaled -> scores in exp2 units
#define THR 10.0f        // defer-max threshold: P bounded by 2^10 (f16-safe)

static __device__ __forceinline__ ushort f32_to_f16u(float f) {
  union { _Float16 h; ushort u; } c;
  c.h = (_Float16)f;
  return c.u;
}
static __device__ __forceinline__ float f16u_to_f32(ushort u) {
  union { _Float16 h; ushort u; } c;
  c.u = u;
  return (float)c.h;
}
// v_cvt_pkrtz_f16_f32: dst = {lo: f16(a), hi: f16(b)}
static __device__ __forceinline__ unsigned cvt_pk_f16(float a, float b) {
  union { fp16x2 h; unsigned u; } c;
  c.h = __builtin_amdgcn_cvt_pkrtz(a, b);
  return c.u;
}
// DPP row_ror-based 16-lane allreduce (VALU pipe)
template <int CTRL>
static __device__ __forceinline__ float row_ror(float x) {
  return __int_as_float(__builtin_amdgcn_update_dpp(
      __float_as_int(x), __float_as_int(x), CTRL, 0xf, 0xf, true));
}
static __device__ __forceinline__ float rmax16(float v) {
  v = fmaxf(v, row_ror<0x121>(v));
  v = fmaxf(v, row_ror<0x122>(v));
  v = fmaxf(v, row_ror<0x124>(v));
  v = fmaxf(v, row_ror<0x128>(v));
  return v;
}
static __device__ __forceinline__ float rsum16(float v) {
  v += row_ror<0x121>(v);
  v += row_ror<0x122>(v);
  v += row_ror<0x124>(v);
  v += row_ror<0x128>(v);
  return v;
}

// ---------------------------------------------------------------------------
// Projection (R13-proven): Wh = (h @ W^T) * CSC -> f16 hi + f16 residual.
// ---------------------------------------------------------------------------
__global__ __launch_bounds__(256) void proj_kernel(const float* __restrict__ hm,
                                                   const float* __restrict__ Wm,
                                                   ushort* __restrict__ whh,
                                                   ushort* __restrict__ whl) {
  __shared__ float sWT[128 * 128];
  __shared__ float sH[64][128];

  const int t = threadIdx.x;
  const long rowbase = (long)blockIdx.x * 64;

  for (int i = t; i < 4096; i += 256) {
    const int o = i & 127, k4 = i >> 7;
    const float4 w = *(const float4*)(Wm + o * 128 + k4 * 4);
    sWT[(k4 * 4 + 0) * 128 + o] = w.x;
    sWT[(k4 * 4 + 1) * 128 + o] = w.y;
    sWT[(k4 * 4 + 2) * 128 + o] = w.z;
    sWT[(k4 * 4 + 3) * 128 + o] = w.w;
  }
  for (int i = t; i < 64 * 128 / 4; i += 256) {
    *((float4*)(&sH[0][0]) + i) = *((const float4*)(hm + rowbase * 128) + i);
  }
  __syncthreads();

  const int oc = (t & 31) * 4;
  const int nr = (t >> 5) * 8;

  float acc[8][4];
#pragma unroll
  for (int r = 0; r < 8; ++r)
#pragma unroll
    for (int j = 0; j < 4; ++j) acc[r][j] = 0.f;

  for (int k = 0; k < 128; ++k) {
    const float4 wv = *(const float4*)(&sWT[k * 128 + oc]);
#pragma unroll
    for (int r = 0; r < 8; ++r) {
      const float hv = sH[nr + r][k];
      acc[r][0] = fmaf(hv, wv.x, acc[r][0]);
      acc[r][1] = fmaf(hv, wv.y, acc[r][1]);
      acc[r][2] = fmaf(hv, wv.z, acc[r][2]);
      acc[r][3] = fmaf(hv, wv.w, acc[r][3]);
    }
  }

  const int hh = oc >> 5;
  const int d0 = oc & 31;
#pragma unroll
  for (int r = 0; r < 8; ++r) {
    const long gn = rowbase + nr + r;
    const long b = gn >> 12;
    const long n = gn & 4095;
    unsigned hi_[4], lo_[4];
#pragma unroll
    for (int j = 0; j < 4; ++j) {
      const float v = acc[r][j] * CSC;
      const ushort h16 = f32_to_f16u(v);
      hi_[j] = h16;
      lo_[j] = f32_to_f16u(v - f16u_to_f32(h16));
    }
    const size_t idx = (((size_t)(b * NH + hh)) * NN + n) * ND + d0;
    uint2 ph, pl;
    ph.x = hi_[0] | (hi_[1] << 16);
    ph.y = hi_[2] | (hi_[3] << 16);
    pl.x = lo_[0] | (lo_[1] << 16);
    pl.y = lo_[2] | (lo_[3] << 16);
    *(uint2*)(whh + idx) = ph;
    *(uint2*)(whl + idx) = pl;
  }
}

// ---------------------------------------------------------------------------
// Flash attention, f16. R14 = R13 + defer-max (THR=10, wave-vote, no DPP on
// common path) + lane-partial l (rsum16 once in epilogue). All LDS layouts,
// staging, score/PV formulas byte-identical to R13.
// ---------------------------------------------------------------------------
__global__ __launch_bounds__(256, 3) void attn_kernel(const ushort* __restrict__ whh,
                                                      const ushort* __restrict__ whl,
                                                      float* __restrict__ out) {
  __shared__ __align__(16) char sK[BK * KSTR];      // 10240 B
  __shared__ __align__(16) char sVt[32 * VSTR];     // 8704 B
  __shared__ __align__(16) char sP[4][6144];        // 24576 B (4096 used + pad)
                                                    // total 43520 B -> 3 blk/CU

  const int t = threadIdx.x;
  const int wid = t >> 6;
  const int lane = t & 63;
  const int qr = lane & 15;
  const int kg = lane >> 4;

  int bid = blockIdx.x;
  bid = (bid & 7) * 128 + (bid >> 3);              // XCD swizzle (1024 % 8 == 0)
  const int qt = bid & 63;
  const int bh = bid >> 6;
  const ushort* __restrict__ baseh = whh + (size_t)bh * NN * ND;
  const ushort* __restrict__ basel = whl + (size_t)bh * NN * ND;

  const int q0 = qt * BQ + wid * 16;

  // Q fragments (A-operand), hi/lo f16: lane holds Q[q0 + qr][kg*8 + j]
  const f16x8 qh = *(const f16x8*)(baseh + (size_t)(q0 + qr) * ND + kg * 8);
  const f16x8 ql = *(const f16x8*)(basel + (size_t)(q0 + qr) * ND + kg * 8);

  // ---- staging geometry (R8-exact): s = wid, (kb, g) from lane ----
  const int kb = lane & 15;
  const int g = lane >> 4;
  const int s = wid;
  const int r0 = g * 32 + kb;                      // rows r0, r0+16
  const unsigned gsrc0 = (unsigned)(r0 * ND + s * 8);
  const unsigned gsrc1 = gsrc0 + 16u * ND;
  const unsigned kdst0 = (unsigned)(r0 * KSTR + ((s ^ (r0 & 3) ^ g) << 4));
  const unsigned kdst1 = kdst0 + 16u * KSTR;
  unsigned vaddr[8];
#pragma unroll
  for (int j = 0; j < 8; ++j) {
    const int d = s * 8 + j;
    const int B16 = (kb & 8) | ((kb + 3 * d + 2 * s) & 7);
    vaddr[j] = (unsigned)(d * VSTR + B16 * 16 + g * 4);
  }

  f32x4 o0 = {0.f, 0.f, 0.f, 0.f};
  f32x4 o1 = {0.f, 0.f, 0.f, 0.f};
  float m_[4], l_[4];
#pragma unroll
  for (int r = 0; r < 4; ++r) { m_[r] = -10000.f; l_[r] = 0.f; }

  // prefetch tile 0 into registers (hi plane only)
  i32x4 vh0 = *(const i32x4*)(baseh + gsrc0);
  i32x4 vh1 = *(const i32x4*)(baseh + gsrc1);

  for (int kt6 = 0; kt6 < 32; ++kt6) {
    __syncthreads();
    // ---- stage K tile (R8 layout, single plane) ----
    *(i32x4*)(&sK[kdst0]) = vh0;
    *(i32x4*)(&sK[kdst1]) = vh1;
    // ---- V^T scatter (R8 layout): u32 = V[r0][d] | V[r0+16][d]<<16 ----
#pragma unroll
    for (int j = 0; j < 8; ++j) {
      const int w = j >> 1;
      const unsigned a = (unsigned)vh0[w], b = (unsigned)vh1[w];
      const unsigned val = (j & 1) ? ((a >> 16) | (b & 0xffff0000u))
                                   : ((a & 0xffffu) | (b << 16));
      *(unsigned*)(&sVt[vaddr[j]]) = val;
    }
    // ---- prefetch next tile ----
    const unsigned nb = (unsigned)(((kt6 + 1) & 31) * BK) * ND;
    vh0 = *(const i32x4*)(baseh + nb + gsrc0);
    vh1 = *(const i32x4*)(baseh + nb + gsrc1);
    __syncthreads();

    // ---- scores S = Qh*K + Ql*K  (Q 22-bit effective, K f16) ----
    f32x4 acc[8];
#pragma unroll
    for (int ks = 0; ks < 8; ++ks) {
      const unsigned koff = (unsigned)((ks * 16 + qr) * KSTR) +
                            (unsigned)(((kg ^ (qr & 3) ^ (ks >> 1)) << 4));
      const f16x8 khf = *(const f16x8*)(&sK[koff]);
      f32x4 z = {0.f, 0.f, 0.f, 0.f};
      z = __builtin_amdgcn_mfma_f32_16x16x32_f16(ql, khf, z, 0, 0, 0);
      z = __builtin_amdgcn_mfma_f32_16x16x32_f16(qh, khf, z, 0, 0, 0);
      acc[ks] = z;
    }

    // ---- leaky relu; y = s' - m (deferred max, lane-local check only) ----
    float pm[4];
#pragma unroll
    for (int r = 0; r < 4; ++r) pm[r] = -INFINITY;
#pragma unroll
    for (int ks = 0; ks < 8; ++ks)
#pragma unroll
      for (int r = 0; r < 4; ++r) {
        float x = acc[ks][r];
        x = fmaxf(x, NEG_SL * x);                // leaky relu (exp2 units)
        const float y = x - m_[r];
        acc[ks][r] = y;
        pm[r] = fmaxf(pm[r], y);
      }
    const float worst = fmaxf(fmaxf(pm[0], pm[1]), fmaxf(pm[2], pm[3]));
    if (__any(worst > THR)) {
      // rare path: raise m to the true row max, rescale running state
#pragma unroll
      for (int r = 0; r < 4; ++r) {
        float d = rmax16(pm[r]);
        d = fmaxf(d, 0.f);                       // keep m monotone
        m_[r] += d;
        const float sc = __builtin_amdgcn_exp2f(-d);
        l_[r] *= sc;
        o0[r] *= sc;
        o1[r] *= sc;
#pragma unroll
        for (int ks = 0; ks < 8; ++ks) acc[ks][r] -= d;
      }
    }

    // ---- p = exp2(y): lane-partial row sum + pkrtz pack; write paired P ----
#pragma unroll
    for (int r = 0; r < 4; ++r) {
      i32x4 pw;
      float rs = 0.f;
#pragma unroll
      for (int w = 0; w < 4; ++w) {
        const float p0 = __builtin_amdgcn_exp2f(acc[2 * w][r]);
        const float p1 = __builtin_amdgcn_exp2f(acc[2 * w + 1][r]);
        rs += p0 + p1;
        pw[w] = (int)cvt_pk_f16(p0, p1);
      }
      l_[r] += rs;                               // lane partial (reduced at end)
      const int rho = kg * 4 + r;
      const int cb = qr ^ (rho & 7);
      *(i32x4*)(&sP[wid][rho * 256 + cb * 16]) = pw;
    }

    // ---- PV: A = paired P, B = V^T (R8-exact read formulas), f16 ----
#pragma unroll
    for (int kp = 0; kp < 4; ++kp) {
      const int kbR = kp * 4 + kg;
      const int cin = kbR + 3 * qr + 2 * (qr >> 3);
      const int cv0 = (kbR & 8) | (cin & 7);
      const int cv1 = (kbR & 8) | ((cin + 4) & 7);
      const f16x8 vb0 = *(const f16x8*)(&sVt[qr * VSTR + cv0 * 16]);
      const f16x8 vb1 = *(const f16x8*)(&sVt[(qr + 16) * VSTR + cv1 * 16]);
      const int cbp = kbR ^ (qr & 7);
      const f16x8 pa = *(const f16x8*)(&sP[wid][qr * 256 + cbp * 16]);
      o0 = __builtin_amdgcn_mfma_f32_16x16x32_f16(pa, vb0, o0, 0, 0, 0);
      o1 = __builtin_amdgcn_mfma_f32_16x16x32_f16(pa, vb1, o1, 0, 0, 0);
    }
  }

  // ---- epilogue: reduce lane-partial l, then out = o / (CSC * l) ----
  const int b = bh >> 2, hh = bh & 3;
#pragma unroll
  for (int r = 0; r < 4; ++r) {
    const float lr = rsum16(l_[r]);
    const int q = q0 + kg * 4 + r;
    const float inv = 1.f / (CSC * lr);
    const size_t rowoff = ((size_t)(b * NN + q)) * 128 + hh * 32;
    out[rowoff + qr] = o0[r] * inv;
    out[rowoff + 16 + qr] = o1[r] * inv;
  }
}

extern "C" void kernel_launch(void* const* d_in, const int* in_sizes, int n_in,
                              void* d_out, int out_size, void* d_ws, size_t ws_size,
                              hipStream_t stream) {
  const float* hm = (const float*)d_in[0];
  const float* Wm = (const float*)d_in[1];
  float* out = (float*)d_out;
  ushort* whh = (ushort*)d_ws;
  ushort* whl = whh + (size_t)NB * NH * NN * ND;   // 8 MB total (proven)

  proj_kernel<<<NB * NN / 64, 256, 0, stream>>>(hm, Wm, whh, whl);
  attn_kernel<<<NB * NH * (NN / BQ), 256, 0, stream>>>(whh, whl, out);
}

// Round 15
// 119.260 us; speedup vs baseline: 1.9675x; 1.0639x over previous
//
#include <hip/hip_runtime.h>

typedef __attribute__((ext_vector_type(8))) _Float16 f16x8;
typedef __attribute__((ext_vector_type(2))) __fp16 fp16x2;
typedef __attribute__((ext_vector_type(4))) float f32x4;
typedef __attribute__((ext_vector_type(4))) int i32x4;

#define NB 4
#define NN 4096
#define NH 4
#define ND 32
#define NEG_SL 0.2f
#define BQ 128
#define BK 128
#define KSTR 80    // K-tile row stride bytes (R8-proven)
#define VSTR 272   // sVt row stride bytes (R8-proven)
#define CSC 1.2011224f   // sqrt(log2(e)); Wh scaled -> scores in exp2 units
#define THR 10.0f        // defer-max threshold: P bounded by 2^10 (f16-safe)

static __device__ __forceinline__ ushort f32_to_f16u(float f) {
  union { _Float16 h; ushort u; } c;
  c.h = (_Float16)f;
  return c.u;
}
static __device__ __forceinline__ float f16u_to_f32(ushort u) {
  union { _Float16 h; ushort u; } c;
  c.u = u;
  return (float)c.h;
}
// v_cvt_pkrtz_f16_f32: dst = {lo: f16(a), hi: f16(b)}
static __device__ __forceinline__ unsigned cvt_pk_f16(float a, float b) {
  union { fp16x2 h; unsigned u; } c;
  c.h = __builtin_amdgcn_cvt_pkrtz(a, b);
  return c.u;
}
// DPP row_ror-based 16-lane allreduce (VALU pipe)
template <int CTRL>
static __device__ __forceinline__ float row_ror(float x) {
  return __int_as_float(__builtin_amdgcn_update_dpp(
      __float_as_int(x), __float_as_int(x), CTRL, 0xf, 0xf, true));
}
static __device__ __forceinline__ float rmax16(float v) {
  v = fmaxf(v, row_ror<0x121>(v));
  v = fmaxf(v, row_ror<0x122>(v));
  v = fmaxf(v, row_ror<0x124>(v));
  v = fmaxf(v, row_ror<0x128>(v));
  return v;
}
static __device__ __forceinline__ float rsum16(float v) {
  v += row_ror<0x121>(v);
  v += row_ror<0x122>(v);
  v += row_ror<0x124>(v);
  v += row_ror<0x128>(v);
  return v;
}

// ---------------------------------------------------------------------------
// Projection (R13-proven): Wh = (h @ W^T) * CSC -> f16 hi + f16 residual.
// ---------------------------------------------------------------------------
__global__ __launch_bounds__(256) void proj_kernel(const float* __restrict__ hm,
                                                   const float* __restrict__ Wm,
                                                   ushort* __restrict__ whh,
                                                   ushort* __restrict__ whl) {
  __shared__ float sWT[128 * 128];
  __shared__ float sH[64][128];

  const int t = threadIdx.x;
  const long rowbase = (long)blockIdx.x * 64;

  for (int i = t; i < 4096; i += 256) {
    const int o = i & 127, k4 = i >> 7;
    const float4 w = *(const float4*)(Wm + o * 128 + k4 * 4);
    sWT[(k4 * 4 + 0) * 128 + o] = w.x;
    sWT[(k4 * 4 + 1) * 128 + o] = w.y;
    sWT[(k4 * 4 + 2) * 128 + o] = w.z;
    sWT[(k4 * 4 + 3) * 128 + o] = w.w;
  }
  for (int i = t; i < 64 * 128 / 4; i += 256) {
    *((float4*)(&sH[0][0]) + i) = *((const float4*)(hm + rowbase * 128) + i);
  }
  __syncthreads();

  const int oc = (t & 31) * 4;
  const int nr = (t >> 5) * 8;

  float acc[8][4];
#pragma unroll
  for (int r = 0; r < 8; ++r)
#pragma unroll
    for (int j = 0; j < 4; ++j) acc[r][j] = 0.f;

  for (int k = 0; k < 128; ++k) {
    const float4 wv = *(const float4*)(&sWT[k * 128 + oc]);
#pragma unroll
    for (int r = 0; r < 8; ++r) {
      const float hv = sH[nr + r][k];
      acc[r][0] = fmaf(hv, wv.x, acc[r][0]);
      acc[r][1] = fmaf(hv, wv.y, acc[r][1]);
      acc[r][2] = fmaf(hv, wv.z, acc[r][2]);
      acc[r][3] = fmaf(hv, wv.w, acc[r][3]);
    }
  }

  const int hh = oc >> 5;
  const int d0 = oc & 31;
#pragma unroll
  for (int r = 0; r < 8; ++r) {
    const long gn = rowbase + nr + r;
    const long b = gn >> 12;
    const long n = gn & 4095;
    unsigned hi_[4], lo_[4];
#pragma unroll
    for (int j = 0; j < 4; ++j) {
      const float v = acc[r][j] * CSC;
      const ushort h16 = f32_to_f16u(v);
      hi_[j] = h16;
      lo_[j] = f32_to_f16u(v - f16u_to_f32(h16));
    }
    const size_t idx = (((size_t)(b * NH + hh)) * NN + n) * ND + d0;
    uint2 ph, pl;
    ph.x = hi_[0] | (hi_[1] << 16);
    ph.y = hi_[2] | (hi_[3] << 16);
    pl.x = lo_[0] | (lo_[1] << 16);
    pl.y = lo_[2] | (lo_[3] << 16);
    *(uint2*)(whh + idx) = ph;
    *(uint2*)(whl + idx) = pl;
  }
}

// ---------------------------------------------------------------------------
// Flash attention, f16, BQ=128 (2 q-frags/wave, R6-proven shape). K and V
// LDS reads shared across both q-frags -> per-q-row ds-ops cut 38%. Composes
// R8 staging/swizzles + R13 f16 single-plane + R14 defer-max. Grid 512,
// 2 blocks/CU tail-free; LDS 51712 B (proven-safe <=3-block regime).
// ---------------------------------------------------------------------------
__global__ __launch_bounds__(256, 2) void attn_kernel(const ushort* __restrict__ whh,
                                                      const ushort* __restrict__ whl,
                                                      float* __restrict__ out) {
  __shared__ __align__(16) char sK[BK * KSTR];      // 10240 B
  __shared__ __align__(16) char sVt[32 * VSTR];     // 8704 B
  __shared__ __align__(16) char sP[4][2][4096];     // 32768 B (total 51712 B)

  const int t = threadIdx.x;
  const int wid = t >> 6;
  const int lane = t & 63;
  const int qr = lane & 15;
  const int kg = lane >> 4;

  int bid = blockIdx.x;
  bid = (bid & 7) * 64 + (bid >> 3);               // XCD swizzle (512 % 8 == 0)
  const int qt = bid & 31;
  const int bh = bid >> 5;
  const ushort* __restrict__ baseh = whh + (size_t)bh * NN * ND;
  const ushort* __restrict__ basel = whl + (size_t)bh * NN * ND;

  const int q0 = qt * BQ + wid * 32;

  // Q fragments (A-operand), hi/lo f16: lane holds Q[q0 + qf*16 + qr][kg*8+j]
  f16x8 qh[2], ql[2];
#pragma unroll
  for (int qf = 0; qf < 2; ++qf) {
    qh[qf] = *(const f16x8*)(baseh + (size_t)(q0 + qf * 16 + qr) * ND + kg * 8);
    ql[qf] = *(const f16x8*)(basel + (size_t)(q0 + qf * 16 + qr) * ND + kg * 8);
  }

  // ---- staging geometry (R8-exact): s = wid, (kb, g) from lane ----
  const int kb = lane & 15;
  const int g = lane >> 4;
  const int s = wid;
  const int r0 = g * 32 + kb;                      // rows r0, r0+16
  const unsigned gsrc0 = (unsigned)(r0 * ND + s * 8);
  const unsigned gsrc1 = gsrc0 + 16u * ND;
  const unsigned kdst0 = (unsigned)(r0 * KSTR + ((s ^ (r0 & 3) ^ g) << 4));
  const unsigned kdst1 = kdst0 + 16u * KSTR;
  unsigned vaddr[8];
#pragma unroll
  for (int j = 0; j < 8; ++j) {
    const int d = s * 8 + j;
    const int B16 = (kb & 8) | ((kb + 3 * d + 2 * s) & 7);
    vaddr[j] = (unsigned)(d * VSTR + B16 * 16 + g * 4);
  }

  f32x4 o[2][2];
#pragma unroll
  for (int qf = 0; qf < 2; ++qf)
#pragma unroll
    for (int pl = 0; pl < 2; ++pl) o[qf][pl] = f32x4{0.f, 0.f, 0.f, 0.f};
  float m_[2][4], l_[2][4];
#pragma unroll
  for (int qf = 0; qf < 2; ++qf)
#pragma unroll
    for (int r = 0; r < 4; ++r) { m_[qf][r] = -10000.f; l_[qf][r] = 0.f; }

  // prefetch tile 0 into registers (hi plane only)
  i32x4 vh0 = *(const i32x4*)(baseh + gsrc0);
  i32x4 vh1 = *(const i32x4*)(baseh + gsrc1);

  for (int kt6 = 0; kt6 < 32; ++kt6) {
    __syncthreads();
    // ---- stage K tile (R8 layout, single plane) ----
    *(i32x4*)(&sK[kdst0]) = vh0;
    *(i32x4*)(&sK[kdst1]) = vh1;
    // ---- V^T scatter (R8 layout): u32 = V[r0][d] | V[r0+16][d]<<16 ----
#pragma unroll
    for (int j = 0; j < 8; ++j) {
      const int w = j >> 1;
      const unsigned a = (unsigned)vh0[w], b = (unsigned)vh1[w];
      const unsigned val = (j & 1) ? ((a >> 16) | (b & 0xffff0000u))
                                   : ((a & 0xffffu) | (b << 16));
      *(unsigned*)(&sVt[vaddr[j]]) = val;
    }
    // ---- prefetch next tile ----
    const unsigned nb = (unsigned)(((kt6 + 1) & 31) * BK) * ND;
    vh0 = *(const i32x4*)(baseh + nb + gsrc0);
    vh1 = *(const i32x4*)(baseh + nb + gsrc1);
    __syncthreads();

    // ---- scores: one K read feeds both q-frags (2 MFMA each) ----
    f32x4 acc[2][8];
#pragma unroll
    for (int ks = 0; ks < 8; ++ks) {
      const unsigned koff = (unsigned)((ks * 16 + qr) * KSTR) +
                            (unsigned)(((kg ^ (qr & 3) ^ (ks >> 1)) << 4));
      const f16x8 khf = *(const f16x8*)(&sK[koff]);
#pragma unroll
      for (int qf = 0; qf < 2; ++qf) {
        f32x4 z = {0.f, 0.f, 0.f, 0.f};
        z = __builtin_amdgcn_mfma_f32_16x16x32_f16(ql[qf], khf, z, 0, 0, 0);
        z = __builtin_amdgcn_mfma_f32_16x16x32_f16(qh[qf], khf, z, 0, 0, 0);
        acc[qf][ks] = z;
      }
    }

    // ---- leaky relu; y = s' - m (deferred max, lane-local check only) ----
    float pm[2][4];
#pragma unroll
    for (int qf = 0; qf < 2; ++qf)
#pragma unroll
      for (int r = 0; r < 4; ++r) pm[qf][r] = -INFINITY;
#pragma unroll
    for (int qf = 0; qf < 2; ++qf)
#pragma unroll
      for (int ks = 0; ks < 8; ++ks)
#pragma unroll
        for (int r = 0; r < 4; ++r) {
          float x = acc[qf][ks][r];
          x = fmaxf(x, NEG_SL * x);              // leaky relu (exp2 units)
          const float y = x - m_[qf][r];
          acc[qf][ks][r] = y;
          pm[qf][r] = fmaxf(pm[qf][r], y);
        }
    float worst = -INFINITY;
#pragma unroll
    for (int qf = 0; qf < 2; ++qf)
#pragma unroll
      for (int r = 0; r < 4; ++r) worst = fmaxf(worst, pm[qf][r]);
    if (__any(worst > THR)) {
      // rare path: raise m to the true row max, rescale running state
#pragma unroll
      for (int qf = 0; qf < 2; ++qf)
#pragma unroll
        for (int r = 0; r < 4; ++r) {
          float d = rmax16(pm[qf][r]);
          d = fmaxf(d, 0.f);                     // keep m monotone
          m_[qf][r] += d;
          const float sc = __builtin_amdgcn_exp2f(-d);
          l_[qf][r] *= sc;
          o[qf][0][r] *= sc;
          o[qf][1][r] *= sc;
#pragma unroll
          for (int ks = 0; ks < 8; ++ks) acc[qf][ks][r] -= d;
        }
    }

    // ---- p = exp2(y): lane-partial row sum + pkrtz pack; write paired P ----
#pragma unroll
    for (int qf = 0; qf < 2; ++qf)
#pragma unroll
      for (int r = 0; r < 4; ++r) {
        i32x4 pw;
        float rs = 0.f;
#pragma unroll
        for (int w = 0; w < 4; ++w) {
          const float p0 = __builtin_amdgcn_exp2f(acc[qf][2 * w][r]);
          const float p1 = __builtin_amdgcn_exp2f(acc[qf][2 * w + 1][r]);
          rs += p0 + p1;
          pw[w] = (int)cvt_pk_f16(p0, p1);
        }
        l_[qf][r] += rs;                         // lane partial
        const int rho = kg * 4 + r;
        const int cb = qr ^ (rho & 7);
        *(i32x4*)(&sP[wid][qf][rho * 256 + cb * 16]) = pw;
      }

    // ---- PV: one V read pair feeds both q-frags ----
#pragma unroll
    for (int kp = 0; kp < 4; ++kp) {
      const int kbR = kp * 4 + kg;
      const int cin = kbR + 3 * qr + 2 * (qr >> 3);
      const int cv0 = (kbR & 8) | (cin & 7);
      const int cv1 = (kbR & 8) | ((cin + 4) & 7);
      const f16x8 vb0 = *(const f16x8*)(&sVt[qr * VSTR + cv0 * 16]);
      const f16x8 vb1 = *(const f16x8*)(&sVt[(qr + 16) * VSTR + cv1 * 16]);
      const int cbp = kbR ^ (qr & 7);
#pragma unroll
      for (int qf = 0; qf < 2; ++qf) {
        const f16x8 pa = *(const f16x8*)(&sP[wid][qf][qr * 256 + cbp * 16]);
        o[qf][0] = __builtin_amdgcn_mfma_f32_16x16x32_f16(pa, vb0, o[qf][0], 0, 0, 0);
        o[qf][1] = __builtin_amdgcn_mfma_f32_16x16x32_f16(pa, vb1, o[qf][1], 0, 0, 0);
      }
    }
  }

  // ---- epilogue: reduce lane-partial l, then out = o / (CSC * l) ----
  const int b = bh >> 2, hh = bh & 3;
#pragma unroll
  for (int qf = 0; qf < 2; ++qf)
#pragma unroll
    for (int r = 0; r < 4; ++r) {
      const float lr = rsum16(l_[qf][r]);
      const int q = q0 + qf * 16 + kg * 4 + r;
      const float inv = 1.f / (CSC * lr);
      const size_t rowoff = ((size_t)(b * NN + q)) * 128 + hh * 32;
      out[rowoff + qr] = o[qf][0][r] * inv;
      out[rowoff + 16 + qr] = o[qf][1][r] * inv;
    }
}

extern "C" void kernel_launch(void* const* d_in, const int* in_sizes, int n_in,
                              void* d_out, int out_size, void* d_ws, size_t ws_size,
                              hipStream_t stream) {
  const float* hm = (const float*)d_in[0];
  const float* Wm = (const float*)d_in[1];
  float* out = (float*)d_out;
  ushort* whh = (ushort*)d_ws;
  ushort* whl = whh + (size_t)NB * NH * NN * ND;   // 8 MB total (proven)

  proj_kernel<<<NB * NN / 64, 256, 0, stream>>>(hm, Wm, whh, whl);
  attn_kernel<<<NB * NH * (NN / BQ), 256, 0, stream>>>(whh, whl, out);
}

// Round 16
// 118.491 us; speedup vs baseline: 1.9802x; 1.0065x over previous
//
#include <hip/hip_runtime.h>

typedef __attribute__((ext_vector_type(8))) _Float16 f16x8;
typedef __attribute__((ext_vector_type(2))) __fp16 fp16x2;
typedef __attribute__((ext_vector_type(4))) float f32x4;
typedef __attribute__((ext_vector_type(4))) int i32x4;

#define NB 4
#define NN 4096
#define NH 4
#define ND 32
#define NEG_SL 0.2f
#define BQ 128
#define BK 128
#define KSTR 80    // K-tile row stride bytes (R8-proven)
#define VSTR 272   // sVt row stride bytes (R8-proven)
#define BUFSZ (BK * KSTR + 32 * VSTR)   // 18944 B per K/Vt buffer
#define CSC 1.2011224f   // sqrt(log2(e)); Wh scaled -> scores in exp2 units
#define THR 10.0f        // defer-max threshold: P bounded by 2^10 (f16-safe)

static __device__ __forceinline__ ushort f32_to_f16u(float f) {
  union { _Float16 h; ushort u; } c;
  c.h = (_Float16)f;
  return c.u;
}
static __device__ __forceinline__ float f16u_to_f32(ushort u) {
  union { _Float16 h; ushort u; } c;
  c.u = u;
  return (float)c.h;
}
// v_cvt_pkrtz_f16_f32: dst = {lo: f16(a), hi: f16(b)}
static __device__ __forceinline__ unsigned cvt_pk_f16(float a, float b) {
  union { fp16x2 h; unsigned u; } c;
  c.h = __builtin_amdgcn_cvt_pkrtz(a, b);
  return c.u;
}
// DPP row_ror-based 16-lane allreduce (VALU pipe)
template <int CTRL>
static __device__ __forceinline__ float row_ror(float x) {
  return __int_as_float(__builtin_amdgcn_update_dpp(
      __float_as_int(x), __float_as_int(x), CTRL, 0xf, 0xf, true));
}
static __device__ __forceinline__ float rmax16(float v) {
  v = fmaxf(v, row_ror<0x121>(v));
  v = fmaxf(v, row_ror<0x122>(v));
  v = fmaxf(v, row_ror<0x124>(v));
  v = fmaxf(v, row_ror<0x128>(v));
  return v;
}
static __device__ __forceinline__ float rsum16(float v) {
  v += row_ror<0x121>(v);
  v += row_ror<0x122>(v);
  v += row_ror<0x124>(v);
  v += row_ror<0x128>(v);
  return v;
}

// ---------------------------------------------------------------------------
// Projection (R13-proven): Wh = (h @ W^T) * CSC -> f16 hi + f16 residual.
// ---------------------------------------------------------------------------
__global__ __launch_bounds__(256) void proj_kernel(const float* __restrict__ hm,
                                                   const float* __restrict__ Wm,
                                                   ushort* __restrict__ whh,
                                                   ushort* __restrict__ whl) {
  __shared__ float sWT[128 * 128];
  __shared__ float sH[64][128];

  const int t = threadIdx.x;
  const long rowbase = (long)blockIdx.x * 64;

  for (int i = t; i < 4096; i += 256) {
    const int o = i & 127, k4 = i >> 7;
    const float4 w = *(const float4*)(Wm + o * 128 + k4 * 4);
    sWT[(k4 * 4 + 0) * 128 + o] = w.x;
    sWT[(k4 * 4 + 1) * 128 + o] = w.y;
    sWT[(k4 * 4 + 2) * 128 + o] = w.z;
    sWT[(k4 * 4 + 3) * 128 + o] = w.w;
  }
  for (int i = t; i < 64 * 128 / 4; i += 256) {
    *((float4*)(&sH[0][0]) + i) = *((const float4*)(hm + rowbase * 128) + i);
  }
  __syncthreads();

  const int oc = (t & 31) * 4;
  const int nr = (t >> 5) * 8;

  float acc[8][4];
#pragma unroll
  for (int r = 0; r < 8; ++r)
#pragma unroll
    for (int j = 0; j < 4; ++j) acc[r][j] = 0.f;

  for (int k = 0; k < 128; ++k) {
    const float4 wv = *(const float4*)(&sWT[k * 128 + oc]);
#pragma unroll
    for (int r = 0; r < 8; ++r) {
      const float hv = sH[nr + r][k];
      acc[r][0] = fmaf(hv, wv.x, acc[r][0]);
      acc[r][1] = fmaf(hv, wv.y, acc[r][1]);
      acc[r][2] = fmaf(hv, wv.z, acc[r][2]);
      acc[r][3] = fmaf(hv, wv.w, acc[r][3]);
    }
  }

  const int hh = oc >> 5;
  const int d0 = oc & 31;
#pragma unroll
  for (int r = 0; r < 8; ++r) {
    const long gn = rowbase + nr + r;
    const long b = gn >> 12;
    const long n = gn & 4095;
    unsigned hi_[4], lo_[4];
#pragma unroll
    for (int j = 0; j < 4; ++j) {
      const float v = acc[r][j] * CSC;
      const ushort h16 = f32_to_f16u(v);
      hi_[j] = h16;
      lo_[j] = f32_to_f16u(v - f16u_to_f32(h16));
    }
    const size_t idx = (((size_t)(b * NH + hh)) * NN + n) * ND + d0;
    uint2 ph, pl;
    ph.x = hi_[0] | (hi_[1] << 16);
    ph.y = hi_[2] | (hi_[3] << 16);
    pl.x = lo_[0] | (lo_[1] << 16);
    pl.y = lo_[2] | (lo_[3] << 16);
    *(uint2*)(whh + idx) = ph;
    *(uint2*)(whl + idx) = pl;
  }
}

// ---------------------------------------------------------------------------
// Flash attention, f16, BQ=128 (R15-proven) + K/Vt DOUBLE-BUFFER with a
// single barrier per tile: barrier -> issue gloads(t+1) -> compute from
// buf[cur] -> write t+1 into buf[cur^1] -> flip. HBM latency hides under
// the full compute phase. LDS 70656 B, 2 blocks/CU (grid-limited anyway).
// All address formulas byte-identical to R15 (+ cur*BUFSZ base).
// ---------------------------------------------------------------------------
__global__ __launch_bounds__(256, 2) void attn_kernel(const ushort* __restrict__ whh,
                                                      const ushort* __restrict__ whl,
                                                      float* __restrict__ out) {
  // [buf][ sK: 10240 | sVt: 8704 ]  x2, then sP (per wave, per qf)
  __shared__ __align__(16) char sMem[2 * BUFSZ + 4 * 2 * 4096];  // 70656 B
  char* const sPbase = sMem + 2 * BUFSZ;

  const int t = threadIdx.x;
  const int wid = t >> 6;
  const int lane = t & 63;
  const int qr = lane & 15;
  const int kg = lane >> 4;
  char* const sPw = sPbase + wid * 8192;

  int bid = blockIdx.x;
  bid = (bid & 7) * 64 + (bid >> 3);               // XCD swizzle (512 % 8 == 0)
  const int qt = bid & 31;
  const int bh = bid >> 5;
  const ushort* __restrict__ baseh = whh + (size_t)bh * NN * ND;
  const ushort* __restrict__ basel = whl + (size_t)bh * NN * ND;

  const int q0 = qt * BQ + wid * 32;

  // Q fragments (A-operand), hi/lo f16: lane holds Q[q0 + qf*16 + qr][kg*8+j]
  f16x8 qh[2], ql[2];
#pragma unroll
  for (int qf = 0; qf < 2; ++qf) {
    qh[qf] = *(const f16x8*)(baseh + (size_t)(q0 + qf * 16 + qr) * ND + kg * 8);
    ql[qf] = *(const f16x8*)(basel + (size_t)(q0 + qf * 16 + qr) * ND + kg * 8);
  }

  // ---- staging geometry (R8-exact): s = wid, (kb, g) from lane ----
  const int kb = lane & 15;
  const int g = lane >> 4;
  const int s = wid;
  const int r0 = g * 32 + kb;                      // rows r0, r0+16
  const unsigned gsrc0 = (unsigned)(r0 * ND + s * 8);
  const unsigned gsrc1 = gsrc0 + 16u * ND;
  const unsigned kdst0 = (unsigned)(r0 * KSTR + ((s ^ (r0 & 3) ^ g) << 4));
  const unsigned kdst1 = kdst0 + 16u * KSTR;
  unsigned vaddr[8];
#pragma unroll
  for (int j = 0; j < 8; ++j) {
    const int d = s * 8 + j;
    const int B16 = (kb & 8) | ((kb + 3 * d + 2 * s) & 7);
    vaddr[j] = (unsigned)(BK * KSTR + d * VSTR + B16 * 16 + g * 4);
  }

  f32x4 o[2][2];
#pragma unroll
  for (int qf = 0; qf < 2; ++qf)
#pragma unroll
    for (int pl = 0; pl < 2; ++pl) o[qf][pl] = f32x4{0.f, 0.f, 0.f, 0.f};
  float m_[2][4], l_[2][4];
#pragma unroll
  for (int qf = 0; qf < 2; ++qf)
#pragma unroll
    for (int r = 0; r < 4; ++r) { m_[qf][r] = -10000.f; l_[qf][r] = 0.f; }

  // ---- prologue: stage tile 0 into buf 0 ----
  {
    const i32x4 a = *(const i32x4*)(baseh + gsrc0);
    const i32x4 b = *(const i32x4*)(baseh + gsrc1);
    *(i32x4*)(&sMem[kdst0]) = a;
    *(i32x4*)(&sMem[kdst1]) = b;
#pragma unroll
    for (int j = 0; j < 8; ++j) {
      const int w = j >> 1;
      const unsigned x = (unsigned)a[w], y = (unsigned)b[w];
      const unsigned val = (j & 1) ? ((x >> 16) | (y & 0xffff0000u))
                                   : ((x & 0xffffu) | (y << 16));
      *(unsigned*)(&sMem[vaddr[j]]) = val;
    }
  }
  int cur = 0;

  for (int kt6 = 0; kt6 < 32; ++kt6) {
    __syncthreads();   // buf[cur] writes visible; prior reads of buf[cur^1] done
    char* const bufC = sMem + cur * BUFSZ;
    char* const bufN = sMem + (cur ^ 1) * BUFSZ;

    // ---- issue next tile's global loads (latency hides under compute) ----
    const unsigned nb = (unsigned)(((kt6 + 1) & 31) * BK) * ND;
    const i32x4 nvh0 = *(const i32x4*)(baseh + nb + gsrc0);
    const i32x4 nvh1 = *(const i32x4*)(baseh + nb + gsrc1);

    // ---- scores: one K read feeds both q-frags (2 MFMA each) ----
    f32x4 acc[2][8];
#pragma unroll
    for (int ks = 0; ks < 8; ++ks) {
      const unsigned koff = (unsigned)((ks * 16 + qr) * KSTR) +
                            (unsigned)(((kg ^ (qr & 3) ^ (ks >> 1)) << 4));
      const f16x8 khf = *(const f16x8*)(&bufC[koff]);
#pragma unroll
      for (int qf = 0; qf < 2; ++qf) {
        f32x4 z = {0.f, 0.f, 0.f, 0.f};
        z = __builtin_amdgcn_mfma_f32_16x16x32_f16(ql[qf], khf, z, 0, 0, 0);
        z = __builtin_amdgcn_mfma_f32_16x16x32_f16(qh[qf], khf, z, 0, 0, 0);
        acc[qf][ks] = z;
      }
    }

    // ---- leaky relu; y = s' - m (deferred max, lane-local check only) ----
    float pm[2][4];
#pragma unroll
    for (int qf = 0; qf < 2; ++qf)
#pragma unroll
      for (int r = 0; r < 4; ++r) pm[qf][r] = -INFINITY;
#pragma unroll
    for (int qf = 0; qf < 2; ++qf)
#pragma unroll
      for (int ks = 0; ks < 8; ++ks)
#pragma unroll
        for (int r = 0; r < 4; ++r) {
          float x = acc[qf][ks][r];
          x = fmaxf(x, NEG_SL * x);              // leaky relu (exp2 units)
          const float y = x - m_[qf][r];
          acc[qf][ks][r] = y;
          pm[qf][r] = fmaxf(pm[qf][r], y);
        }
    float worst = -INFINITY;
#pragma unroll
    for (int qf = 0; qf < 2; ++qf)
#pragma unroll
      for (int r = 0; r < 4; ++r) worst = fmaxf(worst, pm[qf][r]);
    if (__any(worst > THR)) {
      // rare path: raise m to the true row max, rescale running state
#pragma unroll
      for (int qf = 0; qf < 2; ++qf)
#pragma unroll
        for (int r = 0; r < 4; ++r) {
          float d = rmax16(pm[qf][r]);
          d = fmaxf(d, 0.f);                     // keep m monotone
          m_[qf][r] += d;
          const float sc = __builtin_amdgcn_exp2f(-d);
          l_[qf][r] *= sc;
          o[qf][0][r] *= sc;
          o[qf][1][r] *= sc;
#pragma unroll
          for (int ks = 0; ks < 8; ++ks) acc[qf][ks][r] -= d;
        }
    }

    // ---- p = exp2(y): lane-partial row sum + pkrtz pack; write paired P ----
#pragma unroll
    for (int qf = 0; qf < 2; ++qf)
#pragma unroll
      for (int r = 0; r < 4; ++r) {
        i32x4 pw;
        float rs = 0.f;
#pragma unroll
        for (int w = 0; w < 4; ++w) {
          const float p0 = __builtin_amdgcn_exp2f(acc[qf][2 * w][r]);
          const float p1 = __builtin_amdgcn_exp2f(acc[qf][2 * w + 1][r]);
          rs += p0 + p1;
          pw[w] = (int)cvt_pk_f16(p0, p1);
        }
        l_[qf][r] += rs;                         // lane partial
        const int rho = kg * 4 + r;
        const int cb = qr ^ (rho & 7);
        *(i32x4*)(&sPw[qf * 4096 + rho * 256 + cb * 16]) = pw;
      }

    // ---- PV: one V read pair feeds both q-frags ----
#pragma unroll
    for (int kp = 0; kp < 4; ++kp) {
      const int kbR = kp * 4 + kg;
      const int cin = kbR + 3 * qr + 2 * (qr >> 3);
      const int cv0 = (kbR & 8) | (cin & 7);
      const int cv1 = (kbR & 8) | ((cin + 4) & 7);
      const f16x8 vb0 = *(const f16x8*)(&bufC[BK * KSTR + qr * VSTR + cv0 * 16]);
      const f16x8 vb1 = *(const f16x8*)(&bufC[BK * KSTR + (qr + 16) * VSTR + cv1 * 16]);
      const int cbp = kbR ^ (qr & 7);
#pragma unroll
      for (int qf = 0; qf < 2; ++qf) {
        const f16x8 pa = *(const f16x8*)(&sPw[qf * 4096 + qr * 256 + cbp * 16]);
        o[qf][0] = __builtin_amdgcn_mfma_f32_16x16x32_f16(pa, vb0, o[qf][0], 0, 0, 0);
        o[qf][1] = __builtin_amdgcn_mfma_f32_16x16x32_f16(pa, vb1, o[qf][1], 0, 0, 0);
      }
    }

    // ---- write tile t+1 into buf[cur^1] (reads of that buffer finished
    //      before the top-of-loop barrier of THIS iteration) ----
    *(i32x4*)(&bufN[kdst0]) = nvh0;
    *(i32x4*)(&bufN[kdst1]) = nvh1;
#pragma unroll
    for (int j = 0; j < 8; ++j) {
      const int w = j >> 1;
      const unsigned x = (unsigned)nvh0[w], y = (unsigned)nvh1[w];
      const unsigned val = (j & 1) ? ((x >> 16) | (y & 0xffff0000u))
                                   : ((x & 0xffffu) | (y << 16));
      *(unsigned*)(&bufN[vaddr[j]]) = val;
    }
    cur ^= 1;
  }

  // ---- epilogue: reduce lane-partial l, then out = o / (CSC * l) ----
  const int b = bh >> 2, hh = bh & 3;
#pragma unroll
  for (int qf = 0; qf < 2; ++qf)
#pragma unroll
    for (int r = 0; r < 4; ++r) {
      const float lr = rsum16(l_[qf][r]);
      const int q = q0 + qf * 16 + kg * 4 + r;
      const float inv = 1.f / (CSC * lr);
      const size_t rowoff = ((size_t)(b * NN + q)) * 128 + hh * 32;
      out[rowoff + qr] = o[qf][0][r] * inv;
      out[rowoff + 16 + qr] = o[qf][1][r] * inv;
    }
}

extern "C" void kernel_launch(void* const* d_in, const int* in_sizes, int n_in,
                              void* d_out, int out_size, void* d_ws, size_t ws_size,
                              hipStream_t stream) {
  const float* hm = (const float*)d_in[0];
  const float* Wm = (const float*)d_in[1];
  float* out = (float*)d_out;
  ushort* whh = (ushort*)d_ws;
  ushort* whl = whh + (size_t)NB * NH * NN * ND;   // 8 MB total (proven)

  proj_kernel<<<NB * NN / 64, 256, 0, stream>>>(hm, Wm, whh, whl);
  attn_kernel<<<NB * NH * (NN / BQ), 256, 0, stream>>>(whh, whl, out);
}

// Round 17
// 109.691 us; speedup vs baseline: 2.1391x; 1.0802x over previous
//
#include <hip/hip_runtime.h>

typedef __attribute__((ext_vector_type(8))) _Float16 f16x8;
typedef __attribute__((ext_vector_type(2))) __fp16 fp16x2;
typedef __attribute__((ext_vector_type(4))) float f32x4;
typedef __attribute__((ext_vector_type(4))) int i32x4;

#define NB 4
#define NN 4096
#define NH 4
#define ND 32
#define NEG_SL 0.2f
#define BQ 128
#define BK 128
#define KSTR 80    // K-tile row stride bytes (R8-proven)
#define VSTR 272   // sVt row stride bytes (R8-proven)
#define BUFSZ (BK * KSTR + 32 * VSTR)   // 18944 B per K/Vt buffer
#define CSC 1.2011224f   // sqrt(log2(e)); Wh scaled -> scores in exp2 units
#define THR 10.0f        // defer-max threshold: P bounded by 2^10 (f16-safe)

static __device__ __forceinline__ ushort f32_to_f16u(float f) {
  union { _Float16 h; ushort u; } c;
  c.h = (_Float16)f;
  return c.u;
}
// v_cvt_pkrtz_f16_f32: dst = {lo: f16(a), hi: f16(b)}
static __device__ __forceinline__ unsigned cvt_pk_f16(float a, float b) {
  union { fp16x2 h; unsigned u; } c;
  c.h = __builtin_amdgcn_cvt_pkrtz(a, b);
  return c.u;
}
// DPP row_ror-based 16-lane allreduce (VALU pipe)
template <int CTRL>
static __device__ __forceinline__ float row_ror(float x) {
  return __int_as_float(__builtin_amdgcn_update_dpp(
      __float_as_int(x), __float_as_int(x), CTRL, 0xf, 0xf, true));
}
static __device__ __forceinline__ float rmax16(float v) {
  v = fmaxf(v, row_ror<0x121>(v));
  v = fmaxf(v, row_ror<0x122>(v));
  v = fmaxf(v, row_ror<0x124>(v));
  v = fmaxf(v, row_ror<0x128>(v));
  return v;
}
static __device__ __forceinline__ float rsum16(float v) {
  v += row_ror<0x121>(v);
  v += row_ror<0x122>(v);
  v += row_ror<0x124>(v);
  v += row_ror<0x128>(v);
  return v;
}

// ---------------------------------------------------------------------------
// Projection: Wh = (h @ W^T) * CSC -> f16 (single plane; lo residual dropped
// in R17 — f16 rounding is ~0.003 exp2-units in scores, numerically invisible)
// ---------------------------------------------------------------------------
__global__ __launch_bounds__(256) void proj_kernel(const float* __restrict__ hm,
                                                   const float* __restrict__ Wm,
                                                   ushort* __restrict__ whh) {
  __shared__ float sWT[128 * 128];
  __shared__ float sH[64][128];

  const int t = threadIdx.x;
  const long rowbase = (long)blockIdx.x * 64;

  for (int i = t; i < 4096; i += 256) {
    const int o = i & 127, k4 = i >> 7;
    const float4 w = *(const float4*)(Wm + o * 128 + k4 * 4);
    sWT[(k4 * 4 + 0) * 128 + o] = w.x;
    sWT[(k4 * 4 + 1) * 128 + o] = w.y;
    sWT[(k4 * 4 + 2) * 128 + o] = w.z;
    sWT[(k4 * 4 + 3) * 128 + o] = w.w;
  }
  for (int i = t; i < 64 * 128 / 4; i += 256) {
    *((float4*)(&sH[0][0]) + i) = *((const float4*)(hm + rowbase * 128) + i);
  }
  __syncthreads();

  const int oc = (t & 31) * 4;
  const int nr = (t >> 5) * 8;

  float acc[8][4];
#pragma unroll
  for (int r = 0; r < 8; ++r)
#pragma unroll
    for (int j = 0; j < 4; ++j) acc[r][j] = 0.f;

  for (int k = 0; k < 128; ++k) {
    const float4 wv = *(const float4*)(&sWT[k * 128 + oc]);
#pragma unroll
    for (int r = 0; r < 8; ++r) {
      const float hv = sH[nr + r][k];
      acc[r][0] = fmaf(hv, wv.x, acc[r][0]);
      acc[r][1] = fmaf(hv, wv.y, acc[r][1]);
      acc[r][2] = fmaf(hv, wv.z, acc[r][2]);
      acc[r][3] = fmaf(hv, wv.w, acc[r][3]);
    }
  }

  const int hh = oc >> 5;
  const int d0 = oc & 31;
#pragma unroll
  for (int r = 0; r < 8; ++r) {
    const long gn = rowbase + nr + r;
    const long b = gn >> 12;
    const long n = gn & 4095;
    unsigned hi_[4];
#pragma unroll
    for (int j = 0; j < 4; ++j) hi_[j] = f32_to_f16u(acc[r][j] * CSC);
    const size_t idx = (((size_t)(b * NH + hh)) * NN + n) * ND + d0;
    uint2 ph;
    ph.x = hi_[0] | (hi_[1] << 16);
    ph.y = hi_[2] | (hi_[3] << 16);
    *(uint2*)(whh + idx) = ph;
  }
}

// ---------------------------------------------------------------------------
// Flash attention, f16, BQ=128, double-buffered (R16-proven). R17: single-
// MFMA scores (Q lo plane dropped). All layouts/formulas identical to R16.
// ---------------------------------------------------------------------------
__global__ __launch_bounds__(256, 2) void attn_kernel(const ushort* __restrict__ whh,
                                                      float* __restrict__ out) {
  // [buf][ sK: 10240 | sVt: 8704 ]  x2, then sP (per wave, per qf)
  __shared__ __align__(16) char sMem[2 * BUFSZ + 4 * 2 * 4096];  // 70656 B
  char* const sPbase = sMem + 2 * BUFSZ;

  const int t = threadIdx.x;
  const int wid = t >> 6;
  const int lane = t & 63;
  const int qr = lane & 15;
  const int kg = lane >> 4;
  char* const sPw = sPbase + wid * 8192;

  int bid = blockIdx.x;
  bid = (bid & 7) * 64 + (bid >> 3);               // XCD swizzle (512 % 8 == 0)
  const int qt = bid & 31;
  const int bh = bid >> 5;
  const ushort* __restrict__ baseh = whh + (size_t)bh * NN * ND;

  const int q0 = qt * BQ + wid * 32;

  // Q fragments (A-operand), f16: lane holds Q[q0 + qf*16 + qr][kg*8+j]
  f16x8 qh[2];
#pragma unroll
  for (int qf = 0; qf < 2; ++qf)
    qh[qf] = *(const f16x8*)(baseh + (size_t)(q0 + qf * 16 + qr) * ND + kg * 8);

  // ---- staging geometry (R8-exact): s = wid, (kb, g) from lane ----
  const int kb = lane & 15;
  const int g = lane >> 4;
  const int s = wid;
  const int r0 = g * 32 + kb;                      // rows r0, r0+16
  const unsigned gsrc0 = (unsigned)(r0 * ND + s * 8);
  const unsigned gsrc1 = gsrc0 + 16u * ND;
  const unsigned kdst0 = (unsigned)(r0 * KSTR + ((s ^ (r0 & 3) ^ g) << 4));
  const unsigned kdst1 = kdst0 + 16u * KSTR;
  unsigned vaddr[8];
#pragma unroll
  for (int j = 0; j < 8; ++j) {
    const int d = s * 8 + j;
    const int B16 = (kb & 8) | ((kb + 3 * d + 2 * s) & 7);
    vaddr[j] = (unsigned)(BK * KSTR + d * VSTR + B16 * 16 + g * 4);
  }

  f32x4 o[2][2];
#pragma unroll
  for (int qf = 0; qf < 2; ++qf)
#pragma unroll
    for (int pl = 0; pl < 2; ++pl) o[qf][pl] = f32x4{0.f, 0.f, 0.f, 0.f};
  float m_[2][4], l_[2][4];
#pragma unroll
  for (int qf = 0; qf < 2; ++qf)
#pragma unroll
    for (int r = 0; r < 4; ++r) { m_[qf][r] = -10000.f; l_[qf][r] = 0.f; }

  // ---- prologue: stage tile 0 into buf 0 ----
  {
    const i32x4 a = *(const i32x4*)(baseh + gsrc0);
    const i32x4 b = *(const i32x4*)(baseh + gsrc1);
    *(i32x4*)(&sMem[kdst0]) = a;
    *(i32x4*)(&sMem[kdst1]) = b;
#pragma unroll
    for (int j = 0; j < 8; ++j) {
      const int w = j >> 1;
      const unsigned x = (unsigned)a[w], y = (unsigned)b[w];
      const unsigned val = (j & 1) ? ((x >> 16) | (y & 0xffff0000u))
                                   : ((x & 0xffffu) | (y << 16));
      *(unsigned*)(&sMem[vaddr[j]]) = val;
    }
  }
  int cur = 0;

  for (int kt6 = 0; kt6 < 32; ++kt6) {
    __syncthreads();   // buf[cur] writes visible; prior reads of buf[cur^1] done
    char* const bufC = sMem + cur * BUFSZ;
    char* const bufN = sMem + (cur ^ 1) * BUFSZ;

    // ---- issue next tile's global loads (latency hides under compute) ----
    const unsigned nb = (unsigned)(((kt6 + 1) & 31) * BK) * ND;
    const i32x4 nvh0 = *(const i32x4*)(baseh + nb + gsrc0);
    const i32x4 nvh1 = *(const i32x4*)(baseh + nb + gsrc1);

    // ---- scores: one K read, one MFMA per q-frag (lo plane dropped) ----
    f32x4 acc[2][8];
#pragma unroll
    for (int ks = 0; ks < 8; ++ks) {
      const unsigned koff = (unsigned)((ks * 16 + qr) * KSTR) +
                            (unsigned)(((kg ^ (qr & 3) ^ (ks >> 1)) << 4));
      const f16x8 khf = *(const f16x8*)(&bufC[koff]);
#pragma unroll
      for (int qf = 0; qf < 2; ++qf) {
        f32x4 z = {0.f, 0.f, 0.f, 0.f};
        z = __builtin_amdgcn_mfma_f32_16x16x32_f16(qh[qf], khf, z, 0, 0, 0);
        acc[qf][ks] = z;
      }
    }

    // ---- leaky relu; y = s' - m (deferred max, lane-local check only) ----
    float pm[2][4];
#pragma unroll
    for (int qf = 0; qf < 2; ++qf)
#pragma unroll
      for (int r = 0; r < 4; ++r) pm[qf][r] = -INFINITY;
#pragma unroll
    for (int qf = 0; qf < 2; ++qf)
#pragma unroll
      for (int ks = 0; ks < 8; ++ks)
#pragma unroll
        for (int r = 0; r < 4; ++r) {
          float x = acc[qf][ks][r];
          x = fmaxf(x, NEG_SL * x);              // leaky relu (exp2 units)
          const float y = x - m_[qf][r];
          acc[qf][ks][r] = y;
          pm[qf][r] = fmaxf(pm[qf][r], y);
        }
    float worst = -INFINITY;
#pragma unroll
    for (int qf = 0; qf < 2; ++qf)
#pragma unroll
      for (int r = 0; r < 4; ++r) worst = fmaxf(worst, pm[qf][r]);
    if (__any(worst > THR)) {
      // rare path: raise m to the true row max, rescale running state
#pragma unroll
      for (int qf = 0; qf < 2; ++qf)
#pragma unroll
        for (int r = 0; r < 4; ++r) {
          float d = rmax16(pm[qf][r]);
          d = fmaxf(d, 0.f);                     // keep m monotone
          m_[qf][r] += d;
          const float sc = __builtin_amdgcn_exp2f(-d);
          l_[qf][r] *= sc;
          o[qf][0][r] *= sc;
          o[qf][1][r] *= sc;
#pragma unroll
          for (int ks = 0; ks < 8; ++ks) acc[qf][ks][r] -= d;
        }
    }

    // ---- p = exp2(y): lane-partial row sum + pkrtz pack; write paired P ----
#pragma unroll
    for (int qf = 0; qf < 2; ++qf)
#pragma unroll
      for (int r = 0; r < 4; ++r) {
        i32x4 pw;
        float rs = 0.f;
#pragma unroll
        for (int w = 0; w < 4; ++w) {
          const float p0 = __builtin_amdgcn_exp2f(acc[qf][2 * w][r]);
          const float p1 = __builtin_amdgcn_exp2f(acc[qf][2 * w + 1][r]);
          rs += p0 + p1;
          pw[w] = (int)cvt_pk_f16(p0, p1);
        }
        l_[qf][r] += rs;                         // lane partial
        const int rho = kg * 4 + r;
        const int cb = qr ^ (rho & 7);
        *(i32x4*)(&sPw[qf * 4096 + rho * 256 + cb * 16]) = pw;
      }

    // ---- PV: one V read pair feeds both q-frags ----
#pragma unroll
    for (int kp = 0; kp < 4; ++kp) {
      const int kbR = kp * 4 + kg;
      const int cin = kbR + 3 * qr + 2 * (qr >> 3);
      const int cv0 = (kbR & 8) | (cin & 7);
      const int cv1 = (kbR & 8) | ((cin + 4) & 7);
      const f16x8 vb0 = *(const f16x8*)(&bufC[BK * KSTR + qr * VSTR + cv0 * 16]);
      const f16x8 vb1 = *(const f16x8*)(&bufC[BK * KSTR + (qr + 16) * VSTR + cv1 * 16]);
      const int cbp = kbR ^ (qr & 7);
#pragma unroll
      for (int qf = 0; qf < 2; ++qf) {
        const f16x8 pa = *(const f16x8*)(&sPw[qf * 4096 + qr * 256 + cbp * 16]);
        o[qf][0] = __builtin_amdgcn_mfma_f32_16x16x32_f16(pa, vb0, o[qf][0], 0, 0, 0);
        o[qf][1] = __builtin_amdgcn_mfma_f32_16x16x32_f16(pa, vb1, o[qf][1], 0, 0, 0);
      }
    }

    // ---- write tile t+1 into buf[cur^1] ----
    *(i32x4*)(&bufN[kdst0]) = nvh0;
    *(i32x4*)(&bufN[kdst1]) = nvh1;
#pragma unroll
    for (int j = 0; j < 8; ++j) {
      const int w = j >> 1;
      const unsigned x = (unsigned)nvh0[w], y = (unsigned)nvh1[w];
      const unsigned val = (j & 1) ? ((x >> 16) | (y & 0xffff0000u))
                                   : ((x & 0xffffu) | (y << 16));
      *(unsigned*)(&bufN[vaddr[j]]) = val;
    }
    cur ^= 1;
  }

  // ---- epilogue: reduce lane-partial l, then out = o / (CSC * l) ----
  const int b = bh >> 2, hh = bh & 3;
#pragma unroll
  for (int qf = 0; qf < 2; ++qf)
#pragma unroll
    for (int r = 0; r < 4; ++r) {
      const float lr = rsum16(l_[qf][r]);
      const int q = q0 + qf * 16 + kg * 4 + r;
      const float inv = 1.f / (CSC * lr);
      const size_t rowoff = ((size_t)(b * NN + q)) * 128 + hh * 32;
      out[rowoff + qr] = o[qf][0][r] * inv;
      out[rowoff + 16 + qr] = o[qf][1][r] * inv;
    }
}

extern "C" void kernel_launch(void* const* d_in, const int* in_sizes, int n_in,
                              void* d_out, int out_size, void* d_ws, size_t ws_size,
                              hipStream_t stream) {
  const float* hm = (const float*)d_in[0];
  const float* Wm = (const float*)d_in[1];
  float* out = (float*)d_out;
  ushort* whh = (ushort*)d_ws;   // 4 MB used (8 MB available, proven-safe)

  proj_kernel<<<NB * NN / 64, 256, 0, stream>>>(hm, Wm, whh);
  attn_kernel<<<NB * NH * (NN / BQ), 256, 0, stream>>>(whh, out);
}

// Round 18
// 109.147 us; speedup vs baseline: 2.1498x; 1.0050x over previous
//
#include <hip/hip_runtime.h>

typedef __attribute__((ext_vector_type(8))) _Float16 f16x8;
typedef __attribute__((ext_vector_type(2))) __fp16 fp16x2;
typedef __attribute__((ext_vector_type(4))) float f32x4;
typedef __attribute__((ext_vector_type(4))) int i32x4;

#define NB 4
#define NN 4096
#define NH 4
#define ND 32
#define NEG_SL 0.2f
#define BQ 128
#define BK 128
#define KSTR 80    // K-tile row stride bytes (R8-proven)
#define VSTR 272   // sVt row stride bytes (R8-proven)
#define BUFSZ (BK * KSTR + 32 * VSTR)   // 18944 B per K/Vt buffer
#define CSC 1.2011224f   // sqrt(log2(e)); Wh scaled -> scores in exp2 units
#define THR 10.0f        // defer-max threshold: P bounded by 2^10 (f16-safe)

static __device__ __forceinline__ ushort f32_to_f16u(float f) {
  union { _Float16 h; ushort u; } c;
  c.h = (_Float16)f;
  return c.u;
}
// v_cvt_pkrtz_f16_f32: dst = {lo: f16(a), hi: f16(b)}
static __device__ __forceinline__ unsigned cvt_pk_f16(float a, float b) {
  union { fp16x2 h; unsigned u; } c;
  c.h = __builtin_amdgcn_cvt_pkrtz(a, b);
  return c.u;
}
// DPP row_ror-based 16-lane allreduce (VALU pipe)
template <int CTRL>
static __device__ __forceinline__ float row_ror(float x) {
  return __int_as_float(__builtin_amdgcn_update_dpp(
      __float_as_int(x), __float_as_int(x), CTRL, 0xf, 0xf, true));
}
static __device__ __forceinline__ float rmax16(float v) {
  v = fmaxf(v, row_ror<0x121>(v));
  v = fmaxf(v, row_ror<0x122>(v));
  v = fmaxf(v, row_ror<0x124>(v));
  v = fmaxf(v, row_ror<0x128>(v));
  return v;
}
static __device__ __forceinline__ float rsum16(float v) {
  v += row_ror<0x121>(v);
  v += row_ror<0x122>(v);
  v += row_ror<0x124>(v);
  v += row_ror<0x128>(v);
  return v;
}

// ---------------------------------------------------------------------------
// Projection (R17-proven): Wh = (h @ W^T) * CSC -> f16 single plane.
// ---------------------------------------------------------------------------
__global__ __launch_bounds__(256) void proj_kernel(const float* __restrict__ hm,
                                                   const float* __restrict__ Wm,
                                                   ushort* __restrict__ whh) {
  __shared__ float sWT[128 * 128];
  __shared__ float sH[64][128];

  const int t = threadIdx.x;
  const long rowbase = (long)blockIdx.x * 64;

  for (int i = t; i < 4096; i += 256) {
    const int o = i & 127, k4 = i >> 7;
    const float4 w = *(const float4*)(Wm + o * 128 + k4 * 4);
    sWT[(k4 * 4 + 0) * 128 + o] = w.x;
    sWT[(k4 * 4 + 1) * 128 + o] = w.y;
    sWT[(k4 * 4 + 2) * 128 + o] = w.z;
    sWT[(k4 * 4 + 3) * 128 + o] = w.w;
  }
  for (int i = t; i < 64 * 128 / 4; i += 256) {
    *((float4*)(&sH[0][0]) + i) = *((const float4*)(hm + rowbase * 128) + i);
  }
  __syncthreads();

  const int oc = (t & 31) * 4;
  const int nr = (t >> 5) * 8;

  float acc[8][4];
#pragma unroll
  for (int r = 0; r < 8; ++r)
#pragma unroll
    for (int j = 0; j < 4; ++j) acc[r][j] = 0.f;

  for (int k = 0; k < 128; ++k) {
    const float4 wv = *(const float4*)(&sWT[k * 128 + oc]);
#pragma unroll
    for (int r = 0; r < 8; ++r) {
      const float hv = sH[nr + r][k];
      acc[r][0] = fmaf(hv, wv.x, acc[r][0]);
      acc[r][1] = fmaf(hv, wv.y, acc[r][1]);
      acc[r][2] = fmaf(hv, wv.z, acc[r][2]);
      acc[r][3] = fmaf(hv, wv.w, acc[r][3]);
    }
  }

  const int hh = oc >> 5;
  const int d0 = oc & 31;
#pragma unroll
  for (int r = 0; r < 8; ++r) {
    const long gn = rowbase + nr + r;
    const long b = gn >> 12;
    const long n = gn & 4095;
    unsigned hi_[4];
#pragma unroll
    for (int j = 0; j < 4; ++j) hi_[j] = f32_to_f16u(acc[r][j] * CSC);
    const size_t idx = (((size_t)(b * NH + hh)) * NN + n) * ND + d0;
    uint2 ph;
    ph.x = hi_[0] | (hi_[1] << 16);
    ph.y = hi_[2] | (hi_[3] << 16);
    *(uint2*)(whh + idx) = ph;
  }
}

// ---------------------------------------------------------------------------
// Flash attention, f16, BQ=128, double-buffered (R17-proven). R18: setprio
// around MFMA clusters (T5), max3-fused pm reduction, pairwise rs tree.
// All layouts/formulas byte-identical to R17.
// ---------------------------------------------------------------------------
__global__ __launch_bounds__(256, 2) void attn_kernel(const ushort* __restrict__ whh,
                                                      float* __restrict__ out) {
  // [buf][ sK: 10240 | sVt: 8704 ]  x2, then sP (per wave, per qf)
  __shared__ __align__(16) char sMem[2 * BUFSZ + 4 * 2 * 4096];  // 70656 B
  char* const sPbase = sMem + 2 * BUFSZ;

  const int t = threadIdx.x;
  const int wid = t >> 6;
  const int lane = t & 63;
  const int qr = lane & 15;
  const int kg = lane >> 4;
  char* const sPw = sPbase + wid * 8192;

  int bid = blockIdx.x;
  bid = (bid & 7) * 64 + (bid >> 3);               // XCD swizzle (512 % 8 == 0)
  const int qt = bid & 31;
  const int bh = bid >> 5;
  const ushort* __restrict__ baseh = whh + (size_t)bh * NN * ND;

  const int q0 = qt * BQ + wid * 32;

  // Q fragments (A-operand), f16: lane holds Q[q0 + qf*16 + qr][kg*8+j]
  f16x8 qh[2];
#pragma unroll
  for (int qf = 0; qf < 2; ++qf)
    qh[qf] = *(const f16x8*)(baseh + (size_t)(q0 + qf * 16 + qr) * ND + kg * 8);

  // ---- staging geometry (R8-exact): s = wid, (kb, g) from lane ----
  const int kb = lane & 15;
  const int g = lane >> 4;
  const int s = wid;
  const int r0 = g * 32 + kb;                      // rows r0, r0+16
  const unsigned gsrc0 = (unsigned)(r0 * ND + s * 8);
  const unsigned gsrc1 = gsrc0 + 16u * ND;
  const unsigned kdst0 = (unsigned)(r0 * KSTR + ((s ^ (r0 & 3) ^ g) << 4));
  const unsigned kdst1 = kdst0 + 16u * KSTR;
  unsigned vaddr[8];
#pragma unroll
  for (int j = 0; j < 8; ++j) {
    const int d = s * 8 + j;
    const int B16 = (kb & 8) | ((kb + 3 * d + 2 * s) & 7);
    vaddr[j] = (unsigned)(BK * KSTR + d * VSTR + B16 * 16 + g * 4);
  }

  f32x4 o[2][2];
#pragma unroll
  for (int qf = 0; qf < 2; ++qf)
#pragma unroll
    for (int pl = 0; pl < 2; ++pl) o[qf][pl] = f32x4{0.f, 0.f, 0.f, 0.f};
  float m_[2][4], l_[2][4];
#pragma unroll
  for (int qf = 0; qf < 2; ++qf)
#pragma unroll
    for (int r = 0; r < 4; ++r) { m_[qf][r] = -10000.f; l_[qf][r] = 0.f; }

  // ---- prologue: stage tile 0 into buf 0 ----
  {
    const i32x4 a = *(const i32x4*)(baseh + gsrc0);
    const i32x4 b = *(const i32x4*)(baseh + gsrc1);
    *(i32x4*)(&sMem[kdst0]) = a;
    *(i32x4*)(&sMem[kdst1]) = b;
#pragma unroll
    for (int j = 0; j < 8; ++j) {
      const int w = j >> 1;
      const unsigned x = (unsigned)a[w], y = (unsigned)b[w];
      const unsigned val = (j & 1) ? ((x >> 16) | (y & 0xffff0000u))
                                   : ((x & 0xffffu) | (y << 16));
      *(unsigned*)(&sMem[vaddr[j]]) = val;
    }
  }
  int cur = 0;

  for (int kt6 = 0; kt6 < 32; ++kt6) {
    __syncthreads();   // buf[cur] writes visible; prior reads of buf[cur^1] done
    char* const bufC = sMem + cur * BUFSZ;
    char* const bufN = sMem + (cur ^ 1) * BUFSZ;

    // ---- issue next tile's global loads (latency hides under compute) ----
    const unsigned nb = (unsigned)(((kt6 + 1) & 31) * BK) * ND;
    const i32x4 nvh0 = *(const i32x4*)(baseh + nb + gsrc0);
    const i32x4 nvh1 = *(const i32x4*)(baseh + nb + gsrc1);

    // ---- scores: one K read, one MFMA per q-frag ----
    f32x4 acc[2][8];
    __builtin_amdgcn_s_setprio(1);
#pragma unroll
    for (int ks = 0; ks < 8; ++ks) {
      const unsigned koff = (unsigned)((ks * 16 + qr) * KSTR) +
                            (unsigned)(((kg ^ (qr & 3) ^ (ks >> 1)) << 4));
      const f16x8 khf = *(const f16x8*)(&bufC[koff]);
#pragma unroll
      for (int qf = 0; qf < 2; ++qf) {
        f32x4 z = {0.f, 0.f, 0.f, 0.f};
        z = __builtin_amdgcn_mfma_f32_16x16x32_f16(qh[qf], khf, z, 0, 0, 0);
        acc[qf][ks] = z;
      }
    }
    __builtin_amdgcn_s_setprio(0);

    // ---- leaky relu; y = s' - m; pm via max3-fused pairs ----
    float pm[2][4];
#pragma unroll
    for (int qf = 0; qf < 2; ++qf)
#pragma unroll
      for (int r = 0; r < 4; ++r) pm[qf][r] = -INFINITY;
#pragma unroll
    for (int qf = 0; qf < 2; ++qf)
#pragma unroll
      for (int ks = 0; ks < 8; ks += 2)
#pragma unroll
        for (int r = 0; r < 4; ++r) {
          float x0 = acc[qf][ks][r];
          float x1 = acc[qf][ks + 1][r];
          x0 = fmaxf(x0, NEG_SL * x0);
          x1 = fmaxf(x1, NEG_SL * x1);
          const float y0 = x0 - m_[qf][r];
          const float y1 = x1 - m_[qf][r];
          acc[qf][ks][r] = y0;
          acc[qf][ks + 1][r] = y1;
          pm[qf][r] = fmaxf(fmaxf(pm[qf][r], y0), y1);   // v_max3_f32
        }
    const float w0 = fmaxf(fmaxf(pm[0][0], pm[0][1]), pm[0][2]);  // max3
    const float w1 = fmaxf(fmaxf(pm[0][3], pm[1][0]), pm[1][1]);  // max3
    const float w2 = fmaxf(fmaxf(pm[1][2], pm[1][3]), w0);        // max3
    const float worst = fmaxf(w1, w2);
    if (__any(worst > THR)) {
      // rare path: raise m to the true row max, rescale running state
#pragma unroll
      for (int qf = 0; qf < 2; ++qf)
#pragma unroll
        for (int r = 0; r < 4; ++r) {
          float d = rmax16(pm[qf][r]);
          d = fmaxf(d, 0.f);                     // keep m monotone
          m_[qf][r] += d;
          const float sc = __builtin_amdgcn_exp2f(-d);
          l_[qf][r] *= sc;
          o[qf][0][r] *= sc;
          o[qf][1][r] *= sc;
#pragma unroll
          for (int ks = 0; ks < 8; ++ks) acc[qf][ks][r] -= d;
        }
    }

    // ---- p = exp2(y): pairwise rs tree + pkrtz pack; write paired P ----
#pragma unroll
    for (int qf = 0; qf < 2; ++qf)
#pragma unroll
      for (int r = 0; r < 4; ++r) {
        i32x4 pw;
        float ps[8];
#pragma unroll
        for (int w = 0; w < 4; ++w) {
          const float p0 = __builtin_amdgcn_exp2f(acc[qf][2 * w][r]);
          const float p1 = __builtin_amdgcn_exp2f(acc[qf][2 * w + 1][r]);
          ps[2 * w] = p0;
          ps[2 * w + 1] = p1;
          pw[w] = (int)cvt_pk_f16(p0, p1);
        }
        const float s01 = ps[0] + ps[1], s23 = ps[2] + ps[3];
        const float s45 = ps[4] + ps[5], s67 = ps[6] + ps[7];
        l_[qf][r] += (s01 + s23) + (s45 + s67);  // lane partial
        const int rho = kg * 4 + r;
        const int cb = qr ^ (rho & 7);
        *(i32x4*)(&sPw[qf * 4096 + rho * 256 + cb * 16]) = pw;
      }

    // ---- PV: one V read pair feeds both q-frags ----
    __builtin_amdgcn_s_setprio(1);
#pragma unroll
    for (int kp = 0; kp < 4; ++kp) {
      const int kbR = kp * 4 + kg;
      const int cin = kbR + 3 * qr + 2 * (qr >> 3);
      const int cv0 = (kbR & 8) | (cin & 7);
      const int cv1 = (kbR & 8) | ((cin + 4) & 7);
      const f16x8 vb0 = *(const f16x8*)(&bufC[BK * KSTR + qr * VSTR + cv0 * 16]);
      const f16x8 vb1 = *(const f16x8*)(&bufC[BK * KSTR + (qr + 16) * VSTR + cv1 * 16]);
      const int cbp = kbR ^ (qr & 7);
#pragma unroll
      for (int qf = 0; qf < 2; ++qf) {
        const f16x8 pa = *(const f16x8*)(&sPw[qf * 4096 + qr * 256 + cbp * 16]);
        o[qf][0] = __builtin_amdgcn_mfma_f32_16x16x32_f16(pa, vb0, o[qf][0], 0, 0, 0);
        o[qf][1] = __builtin_amdgcn_mfma_f32_16x16x32_f16(pa, vb1, o[qf][1], 0, 0, 0);
      }
    }
    __builtin_amdgcn_s_setprio(0);

    // ---- write tile t+1 into buf[cur^1] ----
    *(i32x4*)(&bufN[kdst0]) = nvh0;
    *(i32x4*)(&bufN[kdst1]) = nvh1;
#pragma unroll
    for (int j = 0; j < 8; ++j) {
      const int w = j >> 1;
      const unsigned x = (unsigned)nvh0[w], y = (unsigned)nvh1[w];
      const unsigned val = (j & 1) ? ((x >> 16) | (y & 0xffff0000u))
                                   : ((x & 0xffffu) | (y << 16));
      *(unsigned*)(&bufN[vaddr[j]]) = val;
    }
    cur ^= 1;
  }

  // ---- epilogue: reduce lane-partial l, then out = o / (CSC * l) ----
  const int b = bh >> 2, hh = bh & 3;
#pragma unroll
  for (int qf = 0; qf < 2; ++qf)
#pragma unroll
    for (int r = 0; r < 4; ++r) {
      const float lr = rsum16(l_[qf][r]);
      const int q = q0 + qf * 16 + kg * 4 + r;
      const float inv = 1.f / (CSC * lr);
      const size_t rowoff = ((size_t)(b * NN + q)) * 128 + hh * 32;
      out[rowoff + qr] = o[qf][0][r] * inv;
      out[rowoff + 16 + qr] = o[qf][1][r] * inv;
    }
}

extern "C" void kernel_launch(void* const* d_in, const int* in_sizes, int n_in,
                              void* d_out, int out_size, void* d_ws, size_t ws_size,
                              hipStream_t stream) {
  const float* hm = (const float*)d_in[0];
  const float* Wm = (const float*)d_in[1];
  float* out = (float*)d_out;
  ushort* whh = (ushort*)d_ws;   // 4 MB used (8 MB available, proven-safe)

  proj_kernel<<<NB * NN / 64, 256, 0, stream>>>(hm, Wm, whh);
  attn_kernel<<<NB * NH * (NN / BQ), 256, 0, stream>>>(whh, out);
}